// Round 1
// baseline (1933.820 us; speedup 1.0000x reference)
//
#include <hip/hip_runtime.h>
#include <math.h>

#define N_NODES  50000
#define N_EDGES  800000
#define E_TOT    (N_EDGES + N_NODES)   // 850000 incl self loops
#define N_GRAPHS 128
#define IN_F     768
#define HID2     128
#define NHID     64

__device__ __forceinline__ float selu_f(float x) {
    const float alpha = 1.6732632423543772f;
    const float scale = 1.0507009873554805f;
    return scale * (x > 0.f ? x : alpha * (expf(x) - 1.f));
}

// order-preserving float<->uint encoding for atomicMax on floats (incl negatives)
__device__ __forceinline__ unsigned fenc(float f) {
    unsigned u = __float_as_uint(f);
    return (u & 0x80000000u) ? ~u : (u | 0x80000000u);
}
__device__ __forceinline__ float fdec(unsigned e) {
    return (e & 0x80000000u) ? __uint_as_float(e & 0x7FFFFFFFu) : __uint_as_float(~e);
}

// C[M x 128] = A[M x K] @ W[K x 128], fp32, BM=32 BK=64, 128 threads
__global__ __launch_bounds__(128) void gemm_n128(
        const float* __restrict__ A, const float* __restrict__ W,
        float* __restrict__ C, int M, int K) {
    __shared__ float At[32][64];
    __shared__ float Wt[64][128];
    const int tid = threadIdx.x;
    const int row0 = blockIdx.x * 32;
    float acc[32];
#pragma unroll
    for (int r = 0; r < 32; r++) acc[r] = 0.f;

    for (int k0 = 0; k0 < K; k0 += 64) {
#pragma unroll
        for (int i = 0; i < 16; i++) {
            int idx = tid + i * 128;
            int r = idx >> 6, c = idx & 63;
            int gr = row0 + r;
            At[r][c] = (gr < M) ? A[(long)gr * K + k0 + c] : 0.f;
        }
#pragma unroll 8
        for (int i = 0; i < 64; i++) {
            Wt[i][tid] = W[(long)(k0 + i) * 128 + tid];
        }
        __syncthreads();
#pragma unroll 4
        for (int k = 0; k < 64; k++) {
            float wv = Wt[k][tid];
#pragma unroll
            for (int r = 0; r < 32; r++) acc[r] = fmaf(At[r][k], wv, acc[r]);
        }
        __syncthreads();
    }
#pragma unroll
    for (int r = 0; r < 32; r++) {
        int gr = row0 + r;
        if (gr < M) C[(long)gr * 128 + tid] = acc[r];
    }
}

// per-node attention logit halves: e_src = xw . a_src, e_dst = xw . a_dst
__global__ void node_e(const float* __restrict__ xw,
                       const float* __restrict__ a_s, const float* __restrict__ a_d,
                       float* __restrict__ e_src, float* __restrict__ e_dst) {
    int i = blockIdx.x * blockDim.x + threadIdx.x;
    if (i >= N_NODES) return;
    const float4* row = (const float4*)(xw + (long)i * HID2);
    float s = 0.f, d = 0.f;
#pragma unroll
    for (int j = 0; j < 32; j++) {
        float4 v = row[j];
        float4 as = ((const float4*)a_s)[j];
        float4 ad = ((const float4*)a_d)[j];
        s += v.x * as.x + v.y * as.y + v.z * as.z + v.w * as.w;
        d += v.x * ad.x + v.y * ad.y + v.z * ad.z + v.w * ad.w;
    }
    e_src[i] = s;
    e_dst[i] = d;
}

// zero all accumulation targets (ws is poisoned 0xAA before every call)
__global__ void prep(float* __restrict__ out, unsigned* __restrict__ m_enc,
                     float* __restrict__ den, float* __restrict__ pooled,
                     float* __restrict__ cnt) {
    int i = blockIdx.x * blockDim.x + threadIdx.x;
    if (i < N_NODES * HID2) out[i] = 0.f;
    if (i < N_NODES) { m_enc[i] = 0u; den[i] = 0.f; }
    if (i < N_GRAPHS * HID2) pooled[i] = 0.f;
    if (i < N_GRAPHS) cnt[i] = 0.f;
}

__global__ void edge_max(const int* __restrict__ ei,
                         const float* __restrict__ e_src, const float* __restrict__ e_dst,
                         float* __restrict__ edge_e, unsigned* __restrict__ m_enc) {
    int e = blockIdx.x * blockDim.x + threadIdx.x;
    if (e >= E_TOT) return;
    int s, d;
    if (e < N_EDGES) { s = ei[e]; d = ei[N_EDGES + e]; }
    else             { s = d = e - N_EDGES; }
    float v = e_src[s] + e_dst[d];
    v = v > 0.f ? v : 0.2f * v;          // leaky_relu(0.2)
    edge_e[e] = v;
    atomicMax(m_enc + d, fenc(v));
}

__global__ void edge_sum(const int* __restrict__ ei,
                         float* __restrict__ edge_e,           // in: e, out: num
                         const unsigned* __restrict__ m_enc,
                         float* __restrict__ den) {
    int e = blockIdx.x * blockDim.x + threadIdx.x;
    if (e >= E_TOT) return;
    int d = (e < N_EDGES) ? ei[N_EDGES + e] : e - N_EDGES;
    float num = expf(edge_e[e] - fdec(m_enc[d]));
    edge_e[e] = num;
    atomicAdd(den + d, num);
}

__global__ void recip_den(float* __restrict__ den) {
    int i = blockIdx.x * blockDim.x + threadIdx.x;
    if (i < N_NODES) den[i] = 1.f / den[i];
}

// out[dst, f] += (num[e] * invden[dst]) * xw[src, f]
__global__ void edge_agg(const int* __restrict__ ei,
                         const float* __restrict__ edge_num,
                         const float* __restrict__ invden,
                         const float* __restrict__ xw,
                         float* __restrict__ out) {
    int t = blockIdx.x * blockDim.x + threadIdx.x;
    if (t >= E_TOT * HID2) return;
    int e = t >> 7;
    int f = t & 127;
    int s, d;
    if (e < N_EDGES) { s = ei[e]; d = ei[N_EDGES + e]; }
    else             { s = d = e - N_EDGES; }
    float alpha = edge_num[e] * invden[d];
    atomicAdd(out + (long)d * HID2 + f, alpha * xw[(long)s * HID2 + f]);
}

__global__ void bias_selu(float* __restrict__ h, const float* __restrict__ b) {
    int i = blockIdx.x * blockDim.x + threadIdx.x;
    if (i >= N_NODES * HID2) return;
    h[i] = selu_f(h[i] + b[i & 127]);
}

__global__ void pool_sum(const float* __restrict__ h, const int* __restrict__ batch,
                         float* __restrict__ pooled, float* __restrict__ cnt) {
    int i = blockIdx.x * blockDim.x + threadIdx.x;
    if (i >= N_NODES * HID2) return;
    int n = i >> 7, f = i & 127;
    int g = batch[n];
    atomicAdd(pooled + g * HID2 + f, h[i]);
    if (f == 0) atomicAdd(cnt + g, 1.f);
}

__global__ void pool_fin(float* __restrict__ pooled, const float* __restrict__ cnt) {
    int i = blockIdx.x * blockDim.x + threadIdx.x;
    if (i >= N_GRAPHS * HID2) return;
    float c = cnt[i >> 7];
    c = c > 1.f ? c : 1.f;
    pooled[i] = selu_f(pooled[i] / c);
}

__global__ void fc1_k(const float* __restrict__ pooled, const float* __restrict__ w,
                      const float* __restrict__ b, float* __restrict__ g) {
    __shared__ float row[HID2];
    int gi = blockIdx.x, j = threadIdx.x;   // 64 threads
    row[j] = pooled[gi * HID2 + j];
    row[j + 64] = pooled[gi * HID2 + 64 + j];
    __syncthreads();
    float acc = b[j];
#pragma unroll
    for (int k = 0; k < HID2; k++) acc = fmaf(row[k], w[k * NHID + j], acc);
    g[gi * NHID + j] = selu_f(acc);
}

__global__ void fc2_k(const float* __restrict__ g, const float* __restrict__ w,
                      const float* __restrict__ b, float* __restrict__ out) {
    int gi = blockIdx.x * blockDim.x + threadIdx.x;
    if (gi >= N_GRAPHS) return;
    float l0 = b[0], l1 = b[1];
#pragma unroll
    for (int k = 0; k < NHID; k++) {
        float v = g[gi * NHID + k];
        l0 = fmaf(v, w[k * 2 + 0], l0);
        l1 = fmaf(v, w[k * 2 + 1], l1);
    }
    float m = fmaxf(l0, l1);
    float lse = m + logf(expf(l0 - m) + expf(l1 - m));
    out[gi * 2 + 0] = l0 - lse;
    out[gi * 2 + 1] = l1 - lse;
}

extern "C" void kernel_launch(void* const* d_in, const int* in_sizes, int n_in,
                              void* d_out, int out_size, void* d_ws, size_t ws_size,
                              hipStream_t stream) {
    const float* x     = (const float*)d_in[0];
    const int*   ei    = (const int*)d_in[1];
    const int*   batch = (const int*)d_in[2];
    const float* W1    = (const float*)d_in[3];
    const float* as1   = (const float*)d_in[4];
    const float* ad1   = (const float*)d_in[5];
    const float* b1    = (const float*)d_in[6];
    const float* W2    = (const float*)d_in[7];
    const float* as2   = (const float*)d_in[8];
    const float* ad2   = (const float*)d_in[9];
    const float* b2    = (const float*)d_in[10];
    const float* fc1w  = (const float*)d_in[11];
    const float* fc1b  = (const float*)d_in[12];
    const float* fc2w  = (const float*)d_in[13];
    const float* fc2b  = (const float*)d_in[14];
    float* out = (float*)d_out;

    // workspace layout (floats)
    float* ws = (float*)d_ws;
    const long NH = (long)N_NODES * HID2;        // 6.4M
    float*    B0      = ws;                      // xw (layer1 then layer2)
    float*    B1      = B0 + NH;                 // h1 (layer1 output)
    float*    B2      = B1 + NH;                 // layer accumulation target
    float*    e_src   = B2 + NH;
    float*    e_dst   = e_src + N_NODES;
    unsigned* m_enc   = (unsigned*)(e_dst + N_NODES);
    float*    den     = (float*)(m_enc + N_NODES);
    float*    edge_b  = den + N_NODES;           // 850000
    float*    pooled  = edge_b + E_TOT;          // 128*128
    float*    cnt     = pooled + N_GRAPHS * HID2;
    float*    g       = cnt + N_GRAPHS;          // 128*64

    const int TB = 256;
    const int gNode  = (N_NODES + TB - 1) / TB;
    const int gNH    = (int)((NH + TB - 1) / TB);
    const int gEdge  = (E_TOT + TB - 1) / TB;
    const int gEdgeF = (int)(((long)E_TOT * HID2 + TB - 1) / TB);

    // ---- layer 1 ----
    gemm_n128<<<(N_NODES + 31) / 32, 128, 0, stream>>>(x, W1, B0, N_NODES, IN_F);
    node_e<<<gNode, TB, 0, stream>>>(B0, as1, ad1, e_src, e_dst);
    prep<<<gNH, TB, 0, stream>>>(B1, m_enc, den, pooled, cnt);
    edge_max<<<gEdge, TB, 0, stream>>>(ei, e_src, e_dst, edge_b, m_enc);
    edge_sum<<<gEdge, TB, 0, stream>>>(ei, edge_b, m_enc, den);
    recip_den<<<gNode, TB, 0, stream>>>(den);
    edge_agg<<<gEdgeF, TB, 0, stream>>>(ei, edge_b, den, B0, B1);
    bias_selu<<<gNH, TB, 0, stream>>>(B1, b1);

    // ---- layer 2 ----
    gemm_n128<<<(N_NODES + 31) / 32, 128, 0, stream>>>(B1, W2, B0, N_NODES, HID2);
    node_e<<<gNode, TB, 0, stream>>>(B0, as2, ad2, e_src, e_dst);
    prep<<<gNH, TB, 0, stream>>>(B2, m_enc, den, pooled, cnt);
    edge_max<<<gEdge, TB, 0, stream>>>(ei, e_src, e_dst, edge_b, m_enc);
    edge_sum<<<gEdge, TB, 0, stream>>>(ei, edge_b, m_enc, den);
    recip_den<<<gNode, TB, 0, stream>>>(den);
    edge_agg<<<gEdgeF, TB, 0, stream>>>(ei, edge_b, den, B0, B2);
    bias_selu<<<gNH, TB, 0, stream>>>(B2, b2);

    // ---- pool + head ----
    pool_sum<<<gNH, TB, 0, stream>>>(B2, batch, pooled, cnt);
    pool_fin<<<(N_GRAPHS * HID2 + TB - 1) / TB, TB, 0, stream>>>(pooled, cnt);
    fc1_k<<<N_GRAPHS, NHID, 0, stream>>>(pooled, fc1w, fc1b, g);
    fc2_k<<<1, 128, 0, stream>>>(g, fc2w, fc2b, out);
}

// Round 2
// 1513.678 us; speedup vs baseline: 1.2776x; 1.2776x over previous
//
#include <hip/hip_runtime.h>
#include <math.h>

#define N_NODES  50000
#define N_EDGES  800000
#define E_TOT    (N_EDGES + N_NODES)   // 850000 incl self loops
#define N_GRAPHS 128
#define IN_F     768
#define HID2     128
#define NHID     64

typedef __attribute__((ext_vector_type(8))) short bf16x8;
typedef __attribute__((ext_vector_type(4))) float f32x4;
typedef __attribute__((ext_vector_type(4))) unsigned short us4;

__device__ __forceinline__ float selu_f(float x) {
    const float alpha = 1.6732632423543772f;
    const float scale = 1.0507009873554805f;
    return scale * (x > 0.f ? x : alpha * (expf(x) - 1.f));
}

// round-to-nearest-even fp32 -> bf16
__device__ __forceinline__ unsigned short f2bf(float f) {
    unsigned u = __float_as_uint(f);
    u += 0x7FFFu + ((u >> 16) & 1u);
    return (unsigned short)(u >> 16);
}

// order-preserving float<->uint encoding for atomicMax on floats (incl negatives)
__device__ __forceinline__ unsigned fenc(float f) {
    unsigned u = __float_as_uint(f);
    return (u & 0x80000000u) ? ~u : (u | 0x80000000u);
}
__device__ __forceinline__ float fdec(unsigned e) {
    return (e & 0x80000000u) ? __uint_as_float(e & 0x7FFFFFFFu) : __uint_as_float(~e);
}

// convert W[K][128] fp32 -> Wt[128][K] bf16 (transposed, for contiguous b-frag reads)
__global__ void wcvt(const float* __restrict__ W, unsigned short* __restrict__ Wt, int K) {
    int i = blockIdx.x * blockDim.x + threadIdx.x;
    if (i >= 128 * K) return;
    int n = i / K, k = i - n * K;
    Wt[i] = f2bf(W[(long)k * 128 + n]);
}

// C[M x 128] = A[M x K] @ B[K x 128], A fp32 (converted in staging), Bt = B^T bf16 [128][K].
// 128x128 tile, 4 waves (2x2), each 64x64 via 4x4 grid of 16x16x32 MFMAs.
#define LDA 40   // padded LDS row stride (bf16 elems): 80 B = 20 banks -> 2-way (free), 16B-aligned
__global__ __launch_bounds__(256) void gemm_mfma(
        const float* __restrict__ A, const unsigned short* __restrict__ Bt,
        float* __restrict__ C, int M, int K) {
    __shared__ unsigned short As[128 * LDA];
    __shared__ unsigned short Bs[128 * LDA];
    const int tid  = threadIdx.x;
    const int row0 = blockIdx.x * 128;
    const int w    = tid >> 6;
    const int lane = tid & 63;
    const int quad = lane >> 4;
    const int l16  = lane & 15;
    const int m_off = (w & 1) * 64;
    const int n_off = (w >> 1) * 64;

    f32x4 acc[4][4];
#pragma unroll
    for (int mi = 0; mi < 4; mi++)
#pragma unroll
        for (int ni = 0; ni < 4; ni++)
            acc[mi][ni] = (f32x4){0.f, 0.f, 0.f, 0.f};

    for (int k0 = 0; k0 < K; k0 += 32) {
        __syncthreads();
        // stage A-tile: 128 rows x 32 k, fp32 -> bf16 (4 float4 loads / thread)
#pragma unroll
        for (int i = 0; i < 4; i++) {
            int p = tid + i * 256;            // 1024 float4 slots
            int r = p >> 3, c4 = p & 7;
            int gr = row0 + r;
            float4 v;
            if (gr < M) v = *(const float4*)&A[(long)gr * K + k0 + c4 * 4];
            else        v = make_float4(0.f, 0.f, 0.f, 0.f);
            us4 o;
            o.x = f2bf(v.x); o.y = f2bf(v.y); o.z = f2bf(v.z); o.w = f2bf(v.w);
            *(us4*)&As[r * LDA + c4 * 4] = o;
        }
        // stage B-tile: Bs[n][k] from Bt rows (2 x 16B copies / thread)
#pragma unroll
        for (int i = 0; i < 2; i++) {
            int c = tid + i * 256;            // 512 ushort8 chunks
            int n = c >> 2, koff = (c & 3) * 8;
            *(bf16x8*)&Bs[n * LDA + koff] = *(const bf16x8*)&Bt[(long)n * K + k0 + koff];
        }
        __syncthreads();

        bf16x8 af[4], bfr[4];
#pragma unroll
        for (int mi = 0; mi < 4; mi++)
            af[mi] = *(const bf16x8*)&As[(m_off + mi * 16 + l16) * LDA + quad * 8];
#pragma unroll
        for (int ni = 0; ni < 4; ni++)
            bfr[ni] = *(const bf16x8*)&Bs[(n_off + ni * 16 + l16) * LDA + quad * 8];
#pragma unroll
        for (int mi = 0; mi < 4; mi++)
#pragma unroll
            for (int ni = 0; ni < 4; ni++)
                acc[mi][ni] = __builtin_amdgcn_mfma_f32_16x16x32_bf16(
                    af[mi], bfr[ni], acc[mi][ni], 0, 0, 0);
    }

    // epilogue: D row = m_off+mi*16+quad*4+r, col = n_off+ni*16+l16
#pragma unroll
    for (int mi = 0; mi < 4; mi++)
#pragma unroll
        for (int r = 0; r < 4; r++) {
            int row = row0 + m_off + mi * 16 + quad * 4 + r;
            if (row < M) {
#pragma unroll
                for (int ni = 0; ni < 4; ni++)
                    C[(long)row * 128 + n_off + ni * 16 + l16] = acc[mi][ni][r];
            }
        }
}

// per-node attention logit halves: e_src = xw . a_src, e_dst = xw . a_dst
__global__ void node_e(const float* __restrict__ xw,
                       const float* __restrict__ a_s, const float* __restrict__ a_d,
                       float* __restrict__ e_src, float* __restrict__ e_dst) {
    int i = blockIdx.x * blockDim.x + threadIdx.x;
    if (i >= N_NODES) return;
    const float4* row = (const float4*)(xw + (long)i * HID2);
    float s = 0.f, d = 0.f;
#pragma unroll
    for (int j = 0; j < 32; j++) {
        float4 v = row[j];
        float4 as = ((const float4*)a_s)[j];
        float4 ad = ((const float4*)a_d)[j];
        s += v.x * as.x + v.y * as.y + v.z * as.z + v.w * as.w;
        d += v.x * ad.x + v.y * ad.y + v.z * ad.z + v.w * ad.w;
    }
    e_src[i] = s;
    e_dst[i] = d;
}

// zero all accumulation targets (ws is poisoned 0xAA before every call)
__global__ void prep(float* __restrict__ out, unsigned* __restrict__ m_enc,
                     float* __restrict__ den, float* __restrict__ pooled,
                     float* __restrict__ cnt) {
    int i = blockIdx.x * blockDim.x + threadIdx.x;
    if (i < N_NODES * HID2) out[i] = 0.f;
    if (i < N_NODES) { m_enc[i] = 0u; den[i] = 0.f; }
    if (i < N_GRAPHS * HID2) pooled[i] = 0.f;
    if (i < N_GRAPHS) cnt[i] = 0.f;
}

__global__ void edge_max(const int* __restrict__ ei,
                         const float* __restrict__ e_src, const float* __restrict__ e_dst,
                         float* __restrict__ edge_e, unsigned* __restrict__ m_enc) {
    int e = blockIdx.x * blockDim.x + threadIdx.x;
    if (e >= E_TOT) return;
    int s, d;
    if (e < N_EDGES) { s = ei[e]; d = ei[N_EDGES + e]; }
    else             { s = d = e - N_EDGES; }
    float v = e_src[s] + e_dst[d];
    v = v > 0.f ? v : 0.2f * v;          // leaky_relu(0.2)
    edge_e[e] = v;
    atomicMax(m_enc + d, fenc(v));
}

__global__ void edge_sum(const int* __restrict__ ei,
                         float* __restrict__ edge_e,           // in: e, out: num
                         const unsigned* __restrict__ m_enc,
                         float* __restrict__ den) {
    int e = blockIdx.x * blockDim.x + threadIdx.x;
    if (e >= E_TOT) return;
    int d = (e < N_EDGES) ? ei[N_EDGES + e] : e - N_EDGES;
    float num = expf(edge_e[e] - fdec(m_enc[d]));
    edge_e[e] = num;
    atomicAdd(den + d, num);
}

__global__ void recip_den(float* __restrict__ den) {
    int i = blockIdx.x * blockDim.x + threadIdx.x;
    if (i < N_NODES) den[i] = 1.f / den[i];
}

// out[dst, f] += (num[e] * invden[dst]) * xw[src, f]
__global__ void edge_agg(const int* __restrict__ ei,
                         const float* __restrict__ edge_num,
                         const float* __restrict__ invden,
                         const float* __restrict__ xw,
                         float* __restrict__ out) {
    int t = blockIdx.x * blockDim.x + threadIdx.x;
    if (t >= E_TOT * HID2) return;
    int e = t >> 7;
    int f = t & 127;
    int s, d;
    if (e < N_EDGES) { s = ei[e]; d = ei[N_EDGES + e]; }
    else             { s = d = e - N_EDGES; }
    float alpha = edge_num[e] * invden[d];
    atomicAdd(out + (long)d * HID2 + f, alpha * xw[(long)s * HID2 + f]);
}

__global__ void bias_selu(float* __restrict__ h, const float* __restrict__ b) {
    int i = blockIdx.x * blockDim.x + threadIdx.x;
    if (i >= N_NODES * HID2) return;
    h[i] = selu_f(h[i] + b[i & 127]);
}

__global__ void pool_sum(const float* __restrict__ h, const int* __restrict__ batch,
                         float* __restrict__ pooled, float* __restrict__ cnt) {
    int i = blockIdx.x * blockDim.x + threadIdx.x;
    if (i >= N_NODES * HID2) return;
    int n = i >> 7, f = i & 127;
    int g = batch[n];
    atomicAdd(pooled + g * HID2 + f, h[i]);
    if (f == 0) atomicAdd(cnt + g, 1.f);
}

__global__ void pool_fin(float* __restrict__ pooled, const float* __restrict__ cnt) {
    int i = blockIdx.x * blockDim.x + threadIdx.x;
    if (i >= N_GRAPHS * HID2) return;
    float c = cnt[i >> 7];
    c = c > 1.f ? c : 1.f;
    pooled[i] = selu_f(pooled[i] / c);
}

__global__ void fc1_k(const float* __restrict__ pooled, const float* __restrict__ w,
                      const float* __restrict__ b, float* __restrict__ g) {
    __shared__ float row[HID2];
    int gi = blockIdx.x, j = threadIdx.x;   // 64 threads
    row[j] = pooled[gi * HID2 + j];
    row[j + 64] = pooled[gi * HID2 + 64 + j];
    __syncthreads();
    float acc = b[j];
#pragma unroll
    for (int k = 0; k < HID2; k++) acc = fmaf(row[k], w[k * NHID + j], acc);
    g[gi * NHID + j] = selu_f(acc);
}

__global__ void fc2_k(const float* __restrict__ g, const float* __restrict__ w,
                      const float* __restrict__ b, float* __restrict__ out) {
    int gi = blockIdx.x * blockDim.x + threadIdx.x;
    if (gi >= N_GRAPHS) return;
    float l0 = b[0], l1 = b[1];
#pragma unroll
    for (int k = 0; k < NHID; k++) {
        float v = g[gi * NHID + k];
        l0 = fmaf(v, w[k * 2 + 0], l0);
        l1 = fmaf(v, w[k * 2 + 1], l1);
    }
    float m = fmaxf(l0, l1);
    float lse = m + logf(expf(l0 - m) + expf(l1 - m));
    out[gi * 2 + 0] = l0 - lse;
    out[gi * 2 + 1] = l1 - lse;
}

extern "C" void kernel_launch(void* const* d_in, const int* in_sizes, int n_in,
                              void* d_out, int out_size, void* d_ws, size_t ws_size,
                              hipStream_t stream) {
    const float* x     = (const float*)d_in[0];
    const int*   ei    = (const int*)d_in[1];
    const int*   batch = (const int*)d_in[2];
    const float* W1    = (const float*)d_in[3];
    const float* as1   = (const float*)d_in[4];
    const float* ad1   = (const float*)d_in[5];
    const float* b1    = (const float*)d_in[6];
    const float* W2    = (const float*)d_in[7];
    const float* as2   = (const float*)d_in[8];
    const float* ad2   = (const float*)d_in[9];
    const float* b2    = (const float*)d_in[10];
    const float* fc1w  = (const float*)d_in[11];
    const float* fc1b  = (const float*)d_in[12];
    const float* fc2w  = (const float*)d_in[13];
    const float* fc2b  = (const float*)d_in[14];
    float* out = (float*)d_out;

    // workspace layout (floats)
    float* ws = (float*)d_ws;
    const long NH = (long)N_NODES * HID2;        // 6.4M
    float*    B0      = ws;                      // xw (layer1 then layer2)
    float*    B1      = B0 + NH;                 // h1 (layer1 output)
    float*    B2      = B1 + NH;                 // layer-2 accumulation target
    float*    e_src   = B2 + NH;
    float*    e_dst   = e_src + N_NODES;
    unsigned* m_enc   = (unsigned*)(e_dst + N_NODES);
    float*    den     = (float*)(m_enc + N_NODES);
    float*    edge_b  = den + N_NODES;           // 850000
    float*    pooled  = edge_b + E_TOT;          // 128*128
    float*    cnt     = pooled + N_GRAPHS * HID2;
    float*    g       = cnt + N_GRAPHS;          // 128*64
    unsigned short* Wt1 = (unsigned short*)(g + N_GRAPHS * NHID);  // 128x768 bf16
    unsigned short* Wt2 = Wt1 + 128 * IN_F;                        // 128x128 bf16

    const int TB = 256;
    const int gNode  = (N_NODES + TB - 1) / TB;
    const int gNH    = (int)((NH + TB - 1) / TB);
    const int gEdge  = (E_TOT + TB - 1) / TB;
    const int gEdgeF = (int)(((long)E_TOT * HID2 + TB - 1) / TB);
    const int gGemm  = (N_NODES + 127) / 128;

    // weight convert+transpose (tiny)
    wcvt<<<(128 * IN_F + TB - 1) / TB, TB, 0, stream>>>(W1, Wt1, IN_F);
    wcvt<<<(128 * HID2 + TB - 1) / TB, TB, 0, stream>>>(W2, Wt2, HID2);

    // ---- layer 1 ----
    gemm_mfma<<<gGemm, 256, 0, stream>>>(x, Wt1, B0, N_NODES, IN_F);
    node_e<<<gNode, TB, 0, stream>>>(B0, as1, ad1, e_src, e_dst);
    prep<<<gNH, TB, 0, stream>>>(B1, m_enc, den, pooled, cnt);
    edge_max<<<gEdge, TB, 0, stream>>>(ei, e_src, e_dst, edge_b, m_enc);
    edge_sum<<<gEdge, TB, 0, stream>>>(ei, edge_b, m_enc, den);
    recip_den<<<gNode, TB, 0, stream>>>(den);
    edge_agg<<<gEdgeF, TB, 0, stream>>>(ei, edge_b, den, B0, B1);
    bias_selu<<<gNH, TB, 0, stream>>>(B1, b1);

    // ---- layer 2 ----
    gemm_mfma<<<gGemm, 256, 0, stream>>>(B1, Wt2, B0, N_NODES, HID2);
    node_e<<<gNode, TB, 0, stream>>>(B0, as2, ad2, e_src, e_dst);
    prep<<<gNH, TB, 0, stream>>>(B2, m_enc, den, pooled, cnt);
    edge_max<<<gEdge, TB, 0, stream>>>(ei, e_src, e_dst, edge_b, m_enc);
    edge_sum<<<gEdge, TB, 0, stream>>>(ei, edge_b, m_enc, den);
    recip_den<<<gNode, TB, 0, stream>>>(den);
    edge_agg<<<gEdgeF, TB, 0, stream>>>(ei, edge_b, den, B0, B2);
    bias_selu<<<gNH, TB, 0, stream>>>(B2, b2);

    // ---- pool + head ----
    pool_sum<<<gNH, TB, 0, stream>>>(B2, batch, pooled, cnt);
    pool_fin<<<(N_GRAPHS * HID2 + TB - 1) / TB, TB, 0, stream>>>(pooled, cnt);
    fc1_k<<<N_GRAPHS, NHID, 0, stream>>>(pooled, fc1w, fc1b, g);
    fc2_k<<<1, 128, 0, stream>>>(g, fc2w, fc2b, out);
}

// Round 3
// 657.946 us; speedup vs baseline: 2.9392x; 2.3006x over previous
//
#include <hip/hip_runtime.h>
#include <math.h>

#define N_NODES  50000
#define N_EDGES  800000
#define E_TOT    (N_EDGES + N_NODES)   // 850000 incl self loops
#define N_GRAPHS 128
#define IN_F     768
#define HID2     128
#define NHID     64

typedef __attribute__((ext_vector_type(8))) short bf16x8;
typedef __attribute__((ext_vector_type(4))) float f32x4;
typedef __attribute__((ext_vector_type(4))) unsigned short us4;

__device__ __forceinline__ float selu_f(float x) {
    const float alpha = 1.6732632423543772f;
    const float scale = 1.0507009873554805f;
    return scale * (x > 0.f ? x : alpha * (expf(x) - 1.f));
}

// round-to-nearest-even fp32 -> bf16
__device__ __forceinline__ unsigned short f2bf(float f) {
    unsigned u = __float_as_uint(f);
    u += 0x7FFFu + ((u >> 16) & 1u);
    return (unsigned short)(u >> 16);
}

// ---------------- GEMM (bf16 MFMA, unchanged from R1) ----------------

// convert W[K][128] fp32 -> Wt[128][K] bf16 (transposed, for contiguous b-frag reads)
__global__ void wcvt(const float* __restrict__ W, unsigned short* __restrict__ Wt, int K) {
    int i = blockIdx.x * blockDim.x + threadIdx.x;
    if (i >= 128 * K) return;
    int n = i / K, k = i - n * K;
    Wt[i] = f2bf(W[(long)k * 128 + n]);
}

#define LDA 40   // padded LDS row stride (bf16): 80 B = 20 banks -> 2-way (free), 16B-aligned
__global__ __launch_bounds__(256) void gemm_mfma(
        const float* __restrict__ A, const unsigned short* __restrict__ Bt,
        float* __restrict__ C, int M, int K) {
    __shared__ unsigned short As[128 * LDA];
    __shared__ unsigned short Bs[128 * LDA];
    const int tid  = threadIdx.x;
    const int row0 = blockIdx.x * 128;
    const int w    = tid >> 6;
    const int lane = tid & 63;
    const int quad = lane >> 4;
    const int l16  = lane & 15;
    const int m_off = (w & 1) * 64;
    const int n_off = (w >> 1) * 64;

    f32x4 acc[4][4];
#pragma unroll
    for (int mi = 0; mi < 4; mi++)
#pragma unroll
        for (int ni = 0; ni < 4; ni++)
            acc[mi][ni] = (f32x4){0.f, 0.f, 0.f, 0.f};

    for (int k0 = 0; k0 < K; k0 += 32) {
        __syncthreads();
#pragma unroll
        for (int i = 0; i < 4; i++) {
            int p = tid + i * 256;
            int r = p >> 3, c4 = p & 7;
            int gr = row0 + r;
            float4 v;
            if (gr < M) v = *(const float4*)&A[(long)gr * K + k0 + c4 * 4];
            else        v = make_float4(0.f, 0.f, 0.f, 0.f);
            us4 o;
            o.x = f2bf(v.x); o.y = f2bf(v.y); o.z = f2bf(v.z); o.w = f2bf(v.w);
            *(us4*)&As[r * LDA + c4 * 4] = o;
        }
#pragma unroll
        for (int i = 0; i < 2; i++) {
            int c = tid + i * 256;
            int n = c >> 2, koff = (c & 3) * 8;
            *(bf16x8*)&Bs[n * LDA + koff] = *(const bf16x8*)&Bt[(long)n * K + k0 + koff];
        }
        __syncthreads();

        bf16x8 af[4], bfr[4];
#pragma unroll
        for (int mi = 0; mi < 4; mi++)
            af[mi] = *(const bf16x8*)&As[(m_off + mi * 16 + l16) * LDA + quad * 8];
#pragma unroll
        for (int ni = 0; ni < 4; ni++)
            bfr[ni] = *(const bf16x8*)&Bs[(n_off + ni * 16 + l16) * LDA + quad * 8];
#pragma unroll
        for (int mi = 0; mi < 4; mi++)
#pragma unroll
            for (int ni = 0; ni < 4; ni++)
                acc[mi][ni] = __builtin_amdgcn_mfma_f32_16x16x32_bf16(
                    af[mi], bfr[ni], acc[mi][ni], 0, 0, 0);
    }

#pragma unroll
    for (int mi = 0; mi < 4; mi++)
#pragma unroll
        for (int r = 0; r < 4; r++) {
            int row = row0 + m_off + mi * 16 + quad * 4 + r;
            if (row < M) {
#pragma unroll
                for (int ni = 0; ni < 4; ni++)
                    C[(long)row * 128 + n_off + ni * 16 + l16] = acc[mi][ni][r];
            }
        }
}

// ---------------- attention logit halves ----------------

__global__ void node_e(const float* __restrict__ xw,
                       const float* __restrict__ a_s, const float* __restrict__ a_d,
                       float* __restrict__ e_src, float* __restrict__ e_dst) {
    int i = blockIdx.x * blockDim.x + threadIdx.x;
    if (i >= N_NODES) return;
    const float4* row = (const float4*)(xw + (long)i * HID2);
    float s = 0.f, d = 0.f;
#pragma unroll
    for (int j = 0; j < 32; j++) {
        float4 v = row[j];
        float4 as = ((const float4*)a_s)[j];
        float4 ad = ((const float4*)a_d)[j];
        s += v.x * as.x + v.y * as.y + v.z * as.z + v.w * as.w;
        d += v.x * ad.x + v.y * ad.y + v.z * ad.z + v.w * ad.w;
    }
    e_src[i] = s;
    e_dst[i] = d;
}

// ---------------- CSR build (once per call) ----------------

__global__ void deg_init(unsigned* __restrict__ deg) {
    int i = blockIdx.x * blockDim.x + threadIdx.x;
    if (i < N_NODES) deg[i] = 1u;   // self loop
}

__global__ void deg_hist(const int* __restrict__ ei, unsigned* __restrict__ deg) {
    int e = blockIdx.x * blockDim.x + threadIdx.x;
    if (e < N_EDGES) atomicAdd(&deg[ei[N_EDGES + e]], 1u);
}

// exclusive scan of deg -> row_ptr[0..N_NODES]. Redundant-prefix per block: block b
// re-sums deg[0, b*256) (20 MB total redundant reads — trivially cheap, no dependency).
__global__ __launch_bounds__(256) void scan_deg(const unsigned* __restrict__ deg,
                                                unsigned* __restrict__ row_ptr) {
    __shared__ unsigned psum_s[4];
    __shared__ unsigned wsum[4];
    int tid = threadIdx.x;
    int wid = tid >> 6, lane = tid & 63;
    int chunk0 = blockIdx.x * 256;

    unsigned psum = 0;
    for (int i = tid; i < chunk0; i += 256) psum += deg[i];
    for (int o = 32; o; o >>= 1) psum += __shfl_xor(psum, o);
    if (lane == 0) psum_s[wid] = psum;

    int i = chunk0 + tid;
    unsigned v = (i < N_NODES) ? deg[i] : 0u;
    unsigned x = v;
    for (int o = 1; o < 64; o <<= 1) {
        unsigned y = __shfl_up(x, o);
        if (lane >= o) x += y;
    }
    if (lane == 63) wsum[wid] = x;
    __syncthreads();
    unsigned base = psum_s[0] + psum_s[1] + psum_s[2] + psum_s[3];
    unsigned wbase = 0;
    for (int k = 0; k < wid; k++) wbase += wsum[k];
    if (i < N_NODES) row_ptr[i] = base + wbase + x - v;
    if (i == N_NODES - 1) row_ptr[N_NODES] = base + wbase + x;
}

// self-loop first in each segment; cursor starts after it
__global__ void csr_seed(const unsigned* __restrict__ row_ptr,
                         unsigned* __restrict__ cursor, unsigned* __restrict__ csr_src) {
    int n = blockIdx.x * blockDim.x + threadIdx.x;
    if (n >= N_NODES) return;
    unsigned p = row_ptr[n];
    csr_src[p] = (unsigned)n;
    cursor[n] = p + 1;
}

__global__ void csr_scatter(const int* __restrict__ ei,
                            unsigned* __restrict__ cursor, unsigned* __restrict__ csr_src) {
    int e = blockIdx.x * blockDim.x + threadIdx.x;
    if (e >= N_EDGES) return;
    int d = ei[N_EDGES + e];
    unsigned p = atomicAdd(&cursor[d], 1u);
    csr_src[p] = (unsigned)ei[e];
}

// ---------------- fused GAT tail: softmax + aggregate + bias + selu ----------------
// one wave per dst node; lane holds features 2*lane, 2*lane+1
__global__ __launch_bounds__(256) void gat_agg(
        const unsigned* __restrict__ row_ptr, const unsigned* __restrict__ csr_src,
        const float* __restrict__ e_src, const float* __restrict__ e_dst,
        const float* __restrict__ xw, const float* __restrict__ bias,
        float* __restrict__ out) {
    int node = blockIdx.x * 4 + (threadIdx.x >> 6);
    if (node >= N_NODES) return;
    int lane = threadIdx.x & 63;
    unsigned beg = row_ptr[node], end = row_ptr[node + 1];
    int deg = (int)(end - beg);
    float ed = e_dst[node];

    // pass 1: segment max
    float m = -INFINITY;
    for (int i = lane; i < deg; i += 64) {
        unsigned s = csr_src[beg + i];
        float e = e_src[s] + ed;
        e = e > 0.f ? e : 0.2f * e;
        m = fmaxf(m, e);
    }
    for (int o = 32; o; o >>= 1) m = fmaxf(m, __shfl_xor(m, o));

    // pass 2: denominator
    float den = 0.f;
    for (int i = lane; i < deg; i += 64) {
        unsigned s = csr_src[beg + i];
        float e = e_src[s] + ed;
        e = e > 0.f ? e : 0.2f * e;
        den += expf(e - m);
    }
    for (int o = 32; o; o >>= 1) den += __shfl_xor(den, o);
    float inv = 1.f / den;

    // pass 3: weighted gather-accumulate
    float a0 = 0.f, a1 = 0.f;
    for (int base = 0; base < deg; base += 64) {
        int i = base + lane;
        int s = 0; float num = 0.f;
        if (i < deg) {
            s = (int)csr_src[beg + i];
            float e = e_src[s] + ed;
            e = e > 0.f ? e : 0.2f * e;
            num = expf(e - m) * inv;
        }
        int cnt = deg - base; if (cnt > 64) cnt = 64;
        for (int j = 0; j < cnt; j++) {
            float alpha = __shfl(num, j);
            int   src   = __shfl(s, j);
            float2 v = *(const float2*)&xw[(long)src * HID2 + lane * 2];
            a0 = fmaf(alpha, v.x, a0);
            a1 = fmaf(alpha, v.y, a1);
        }
    }
    out[(long)node * HID2 + lane * 2]     = selu_f(a0 + bias[lane * 2]);
    out[(long)node * HID2 + lane * 2 + 1] = selu_f(a1 + bias[lane * 2 + 1]);
}

// ---------------- pooling: one block per graph, binary search on sorted batch ----------------
__global__ __launch_bounds__(256) void pool_graph(
        const float* __restrict__ h, const int* __restrict__ batch,
        float* __restrict__ pooled) {
    int g = blockIdx.x;
    int lo = 0, hi = N_NODES;
    while (lo < hi) { int mid = (lo + hi) >> 1; if (batch[mid] < g) lo = mid + 1; else hi = mid; }
    int start = lo;
    lo = start; hi = N_NODES;
    while (lo < hi) { int mid = (lo + hi) >> 1; if (batch[mid] < g + 1) lo = mid + 1; else hi = mid; }
    int end = lo;

    int f = threadIdx.x & 127, half = threadIdx.x >> 7;
    float acc = 0.f;
    for (int n = start + half; n < end; n += 2) acc += h[(long)n * HID2 + f];
    __shared__ float part[HID2];
    if (half == 0) part[f] = acc;
    __syncthreads();
    if (half == 1) {
        float tot = part[f] + acc;
        float c = (float)(end - start);
        c = c > 1.f ? c : 1.f;
        pooled[g * HID2 + f] = selu_f(tot / c);
    }
}

// ---------------- head ----------------
__global__ void fc1_k(const float* __restrict__ pooled, const float* __restrict__ w,
                      const float* __restrict__ b, float* __restrict__ g) {
    __shared__ float row[HID2];
    int gi = blockIdx.x, j = threadIdx.x;   // 64 threads
    row[j] = pooled[gi * HID2 + j];
    row[j + 64] = pooled[gi * HID2 + 64 + j];
    __syncthreads();
    float acc = b[j];
#pragma unroll
    for (int k = 0; k < HID2; k++) acc = fmaf(row[k], w[k * NHID + j], acc);
    g[gi * NHID + j] = selu_f(acc);
}

__global__ void fc2_k(const float* __restrict__ g, const float* __restrict__ w,
                      const float* __restrict__ b, float* __restrict__ out) {
    int gi = blockIdx.x * blockDim.x + threadIdx.x;
    if (gi >= N_GRAPHS) return;
    float l0 = b[0], l1 = b[1];
#pragma unroll
    for (int k = 0; k < NHID; k++) {
        float v = g[gi * NHID + k];
        l0 = fmaf(v, w[k * 2 + 0], l0);
        l1 = fmaf(v, w[k * 2 + 1], l1);
    }
    float m = fmaxf(l0, l1);
    float lse = m + logf(expf(l0 - m) + expf(l1 - m));
    out[gi * 2 + 0] = l0 - lse;
    out[gi * 2 + 1] = l1 - lse;
}

extern "C" void kernel_launch(void* const* d_in, const int* in_sizes, int n_in,
                              void* d_out, int out_size, void* d_ws, size_t ws_size,
                              hipStream_t stream) {
    const float* x     = (const float*)d_in[0];
    const int*   ei    = (const int*)d_in[1];
    const int*   batch = (const int*)d_in[2];
    const float* W1    = (const float*)d_in[3];
    const float* as1   = (const float*)d_in[4];
    const float* ad1   = (const float*)d_in[5];
    const float* b1    = (const float*)d_in[6];
    const float* W2    = (const float*)d_in[7];
    const float* as2   = (const float*)d_in[8];
    const float* ad2   = (const float*)d_in[9];
    const float* b2    = (const float*)d_in[10];
    const float* fc1w  = (const float*)d_in[11];
    const float* fc1b  = (const float*)d_in[12];
    const float* fc2w  = (const float*)d_in[13];
    const float* fc2b  = (const float*)d_in[14];
    float* out = (float*)d_out;

    // workspace layout
    float* ws = (float*)d_ws;
    const long NH = (long)N_NODES * HID2;        // 6.4M
    float*    B0      = ws;                      // xw (layer1 then layer2)
    float*    B1      = B0 + NH;                 // h1
    float*    B2      = B1 + NH;                 // h2
    float*    e_src   = B2 + NH;
    float*    e_dst   = e_src + N_NODES;
    unsigned* deg     = (unsigned*)(e_dst + N_NODES);   // also cursor
    unsigned* row_ptr = deg + N_NODES;                  // N_NODES+1
    unsigned* csr_src = row_ptr + N_NODES + 1;          // E_TOT
    float*    pooled  = (float*)(csr_src + E_TOT);
    float*    g       = pooled + N_GRAPHS * HID2;
    unsigned short* Wt1 = (unsigned short*)(g + N_GRAPHS * NHID);  // 128x768 bf16
    unsigned short* Wt2 = Wt1 + 128 * IN_F;                        // 128x128 bf16

    const int TB = 256;
    const int gNode = (N_NODES + TB - 1) / TB;
    const int gEdge = (N_EDGES + TB - 1) / TB;
    const int gGemm = (N_NODES + 127) / 128;
    const int gAgg  = (N_NODES + 3) / 4;

    // weight convert+transpose (tiny)
    wcvt<<<(128 * IN_F + TB - 1) / TB, TB, 0, stream>>>(W1, Wt1, IN_F);
    wcvt<<<(128 * HID2 + TB - 1) / TB, TB, 0, stream>>>(W2, Wt2, HID2);

    // CSR build (shared by both layers)
    deg_init<<<gNode, TB, 0, stream>>>(deg);
    deg_hist<<<gEdge, TB, 0, stream>>>(ei, deg);
    scan_deg<<<gNode, TB, 0, stream>>>(deg, row_ptr);
    csr_seed<<<gNode, TB, 0, stream>>>(row_ptr, deg, csr_src);   // deg reused as cursor
    csr_scatter<<<gEdge, TB, 0, stream>>>(ei, deg, csr_src);

    // ---- layer 1 ----
    gemm_mfma<<<gGemm, 256, 0, stream>>>(x, Wt1, B0, N_NODES, IN_F);
    node_e<<<gNode, TB, 0, stream>>>(B0, as1, ad1, e_src, e_dst);
    gat_agg<<<gAgg, 256, 0, stream>>>(row_ptr, csr_src, e_src, e_dst, B0, b1, B1);

    // ---- layer 2 ----
    gemm_mfma<<<gGemm, 256, 0, stream>>>(B1, Wt2, B0, N_NODES, HID2);
    node_e<<<gNode, TB, 0, stream>>>(B0, as2, ad2, e_src, e_dst);
    gat_agg<<<gAgg, 256, 0, stream>>>(row_ptr, csr_src, e_src, e_dst, B0, b2, B2);

    // ---- pool + head ----
    pool_graph<<<N_GRAPHS, 256, 0, stream>>>(B2, batch, pooled);
    fc1_k<<<N_GRAPHS, NHID, 0, stream>>>(pooled, fc1w, fc1b, g);
    fc2_k<<<1, 128, 0, stream>>>(g, fc2w, fc2b, out);
}

// Round 4
// 628.986 us; speedup vs baseline: 3.0745x; 1.0460x over previous
//
#include <hip/hip_runtime.h>
#include <math.h>

#define N_NODES  50000
#define N_EDGES  800000
#define E_TOT    (N_EDGES + N_NODES)   // 850000 incl self loops
#define N_GRAPHS 128
#define IN_F     768
#define HID2     128
#define NHID     64

typedef __attribute__((ext_vector_type(8))) short bf16x8;
typedef __attribute__((ext_vector_type(4))) float f32x4;
typedef __attribute__((ext_vector_type(4))) unsigned short us4;

__device__ __forceinline__ float selu_f(float x) {
    const float alpha = 1.6732632423543772f;
    const float scale = 1.0507009873554805f;
    return scale * (x > 0.f ? x : alpha * (expf(x) - 1.f));
}

// round-to-nearest-even fp32 -> bf16
__device__ __forceinline__ unsigned short f2bf(float f) {
    unsigned u = __float_as_uint(f);
    u += 0x7FFFu + ((u >> 16) & 1u);
    return (unsigned short)(u >> 16);
}

// ---------------- GEMM: bf16 MFMA, M-tile 64, BK=64, register-prefetch pipeline ----------------

// convert W[K][128] fp32 -> Wt[128][K] bf16 (transposed, for contiguous b-frag reads)
__global__ void wcvt(const float* __restrict__ W, unsigned short* __restrict__ Wt, int K) {
    int i = blockIdx.x * blockDim.x + threadIdx.x;
    if (i >= 128 * K) return;
    int n = i / K, k = i - n * K;
    Wt[i] = f2bf(W[(long)k * 128 + n]);
}

#define LDA2 72   // padded LDS row stride (bf16): 144 B; frag reads verified conflict-free
__global__ __launch_bounds__(256) void gemm_mfma(
        const float* __restrict__ A, const unsigned short* __restrict__ Bt,
        float* __restrict__ C, int M, int K) {
    __shared__ unsigned short As[64 * LDA2];    // 9.2 KB
    __shared__ unsigned short Bs[128 * LDA2];   // 18.4 KB
    const int tid  = threadIdx.x;
    const int row0 = blockIdx.x * 64;
    const int w    = tid >> 6;
    const int lane = tid & 63;
    const int quad = lane >> 4;
    const int l16  = lane & 15;
    const int m_off = (w & 1) * 32;   // wave covers 32 rows
    const int n_off = (w >> 1) * 64;  // x 64 cols

    f32x4 acc[2][4];
#pragma unroll
    for (int mi = 0; mi < 2; mi++)
#pragma unroll
        for (int ni = 0; ni < 4; ni++)
            acc[mi][ni] = (f32x4){0.f, 0.f, 0.f, 0.f};

    float4 aR[4];
    bf16x8 bR[4];
    // prologue: load tile 0 into registers
#pragma unroll
    for (int i = 0; i < 4; i++) {
        int p = tid + i * 256;
        int r = p >> 4, c4 = p & 15;       // 64 rows x 16 float4
        int gr = row0 + r;
        aR[i] = (gr < M) ? *(const float4*)&A[(long)gr * K + c4 * 4]
                         : make_float4(0.f, 0.f, 0.f, 0.f);
    }
#pragma unroll
    for (int i = 0; i < 4; i++) {
        int c = tid + i * 256;
        int n = c >> 3, koff = (c & 7) * 8;  // 128 rows x 8 chunks
        bR[i] = *(const bf16x8*)&Bt[(long)n * K + koff];
    }

    for (int k0 = 0; k0 < K; k0 += 64) {
        // store current tile regs -> LDS (fp32->bf16 convert for A)
#pragma unroll
        for (int i = 0; i < 4; i++) {
            int p = tid + i * 256;
            int r = p >> 4, c4 = p & 15;
            us4 o;
            o.x = f2bf(aR[i].x); o.y = f2bf(aR[i].y);
            o.z = f2bf(aR[i].z); o.w = f2bf(aR[i].w);
            *(us4*)&As[r * LDA2 + c4 * 4] = o;
        }
#pragma unroll
        for (int i = 0; i < 4; i++) {
            int c = tid + i * 256;
            int n = c >> 3, koff = (c & 7) * 8;
            *(bf16x8*)&Bs[n * LDA2 + koff] = bR[i];
        }
        __syncthreads();

        // issue next tile's global loads (latency overlaps MFMA below)
        if (k0 + 64 < K) {
            int k1 = k0 + 64;
#pragma unroll
            for (int i = 0; i < 4; i++) {
                int p = tid + i * 256;
                int r = p >> 4, c4 = p & 15;
                int gr = row0 + r;
                aR[i] = (gr < M) ? *(const float4*)&A[(long)gr * K + k1 + c4 * 4]
                                 : make_float4(0.f, 0.f, 0.f, 0.f);
            }
#pragma unroll
            for (int i = 0; i < 4; i++) {
                int c = tid + i * 256;
                int n = c >> 3, koff = (c & 7) * 8;
                bR[i] = *(const bf16x8*)&Bt[(long)n * K + k1 + koff];
            }
        }

        // frags + MFMA (BK=64 -> two K=32 steps)
        bf16x8 af[2][2], bfr[2][4];
#pragma unroll
        for (int kk = 0; kk < 2; kk++) {
#pragma unroll
            for (int mi = 0; mi < 2; mi++)
                af[kk][mi] = *(const bf16x8*)&As[(m_off + mi * 16 + l16) * LDA2 + kk * 32 + quad * 8];
#pragma unroll
            for (int ni = 0; ni < 4; ni++)
                bfr[kk][ni] = *(const bf16x8*)&Bs[(n_off + ni * 16 + l16) * LDA2 + kk * 32 + quad * 8];
        }
#pragma unroll
        for (int kk = 0; kk < 2; kk++)
#pragma unroll
            for (int mi = 0; mi < 2; mi++)
#pragma unroll
                for (int ni = 0; ni < 4; ni++)
                    acc[mi][ni] = __builtin_amdgcn_mfma_f32_16x16x32_bf16(
                        af[kk][mi], bfr[kk][ni], acc[mi][ni], 0, 0, 0);
        __syncthreads();
    }

    // epilogue: D row = m_off+mi*16+quad*4+r, col = n_off+ni*16+l16
#pragma unroll
    for (int mi = 0; mi < 2; mi++)
#pragma unroll
        for (int r = 0; r < 4; r++) {
            int row = row0 + m_off + mi * 16 + quad * 4 + r;
            if (row < M) {
#pragma unroll
                for (int ni = 0; ni < 4; ni++)
                    C[(long)row * 128 + n_off + ni * 16 + l16] = acc[mi][ni][r];
            }
        }
}

// ---------------- attention logit halves ----------------

__global__ void node_e(const float* __restrict__ xw,
                       const float* __restrict__ a_s, const float* __restrict__ a_d,
                       float* __restrict__ e_src, float* __restrict__ e_dst) {
    int i = blockIdx.x * blockDim.x + threadIdx.x;
    if (i >= N_NODES) return;
    const float4* row = (const float4*)(xw + (long)i * HID2);
    float s = 0.f, d = 0.f;
#pragma unroll
    for (int j = 0; j < 32; j++) {
        float4 v = row[j];
        float4 as = ((const float4*)a_s)[j];
        float4 ad = ((const float4*)a_d)[j];
        s += v.x * as.x + v.y * as.y + v.z * as.z + v.w * as.w;
        d += v.x * ad.x + v.y * ad.y + v.z * ad.z + v.w * ad.w;
    }
    e_src[i] = s;
    e_dst[i] = d;
}

// ---------------- CSR build (once per call) ----------------

__global__ void deg_init(unsigned* __restrict__ deg) {
    int i = blockIdx.x * blockDim.x + threadIdx.x;
    if (i < N_NODES) deg[i] = 1u;   // self loop
}

__global__ void deg_hist(const int* __restrict__ ei, unsigned* __restrict__ deg) {
    int e = blockIdx.x * blockDim.x + threadIdx.x;
    if (e < N_EDGES) atomicAdd(&deg[ei[N_EDGES + e]], 1u);
}

// exclusive scan of deg -> row_ptr[0..N_NODES]. Redundant-prefix per block.
__global__ __launch_bounds__(256) void scan_deg(const unsigned* __restrict__ deg,
                                                unsigned* __restrict__ row_ptr) {
    __shared__ unsigned psum_s[4];
    __shared__ unsigned wsum[4];
    int tid = threadIdx.x;
    int wid = tid >> 6, lane = tid & 63;
    int chunk0 = blockIdx.x * 256;

    unsigned psum = 0;
    for (int i = tid; i < chunk0; i += 256) psum += deg[i];
    for (int o = 32; o; o >>= 1) psum += __shfl_xor(psum, o);
    if (lane == 0) psum_s[wid] = psum;

    int i = chunk0 + tid;
    unsigned v = (i < N_NODES) ? deg[i] : 0u;
    unsigned x = v;
    for (int o = 1; o < 64; o <<= 1) {
        unsigned y = __shfl_up(x, o);
        if (lane >= o) x += y;
    }
    if (lane == 63) wsum[wid] = x;
    __syncthreads();
    unsigned base = psum_s[0] + psum_s[1] + psum_s[2] + psum_s[3];
    unsigned wbase = 0;
    for (int k = 0; k < wid; k++) wbase += wsum[k];
    if (i < N_NODES) row_ptr[i] = base + wbase + x - v;
    if (i == N_NODES - 1) row_ptr[N_NODES] = base + wbase + x;
}

// self-loop first in each segment; cursor starts after it
__global__ void csr_seed(const unsigned* __restrict__ row_ptr,
                         unsigned* __restrict__ cursor, unsigned* __restrict__ csr_src) {
    int n = blockIdx.x * blockDim.x + threadIdx.x;
    if (n >= N_NODES) return;
    unsigned p = row_ptr[n];
    csr_src[p] = (unsigned)n;
    cursor[n] = p + 1;
}

__global__ void csr_scatter(const int* __restrict__ ei,
                            unsigned* __restrict__ cursor, unsigned* __restrict__ csr_src) {
    int e = blockIdx.x * blockDim.x + threadIdx.x;
    if (e >= N_EDGES) return;
    int d = ei[N_EDGES + e];
    unsigned p = atomicAdd(&cursor[d], 1u);
    csr_src[p] = (unsigned)ei[e];
}

// ---------------- fused GAT tail: softmax + aggregate + bias + selu ----------------
// one wave per dst node; lane holds features 2*lane, 2*lane+1
__global__ __launch_bounds__(256) void gat_agg(
        const unsigned* __restrict__ row_ptr, const unsigned* __restrict__ csr_src,
        const float* __restrict__ e_src, const float* __restrict__ e_dst,
        const float* __restrict__ xw, const float* __restrict__ bias,
        float* __restrict__ out) {
    int node = blockIdx.x * 4 + (threadIdx.x >> 6);
    if (node >= N_NODES) return;
    int lane = threadIdx.x & 63;
    unsigned beg = row_ptr[node], end = row_ptr[node + 1];
    int deg = (int)(end - beg);
    float ed = e_dst[node];

    // pass 1: segment max
    float m = -INFINITY;
    for (int i = lane; i < deg; i += 64) {
        unsigned s = csr_src[beg + i];
        float e = e_src[s] + ed;
        e = e > 0.f ? e : 0.2f * e;
        m = fmaxf(m, e);
    }
    for (int o = 32; o; o >>= 1) m = fmaxf(m, __shfl_xor(m, o));

    // pass 2: denominator
    float den = 0.f;
    for (int i = lane; i < deg; i += 64) {
        unsigned s = csr_src[beg + i];
        float e = e_src[s] + ed;
        e = e > 0.f ? e : 0.2f * e;
        den += expf(e - m);
    }
    for (int o = 32; o; o >>= 1) den += __shfl_xor(den, o);
    float inv = 1.f / den;

    // pass 3: weighted gather-accumulate
    float a0 = 0.f, a1 = 0.f;
    for (int base = 0; base < deg; base += 64) {
        int i = base + lane;
        int s = 0; float num = 0.f;
        if (i < deg) {
            s = (int)csr_src[beg + i];
            float e = e_src[s] + ed;
            e = e > 0.f ? e : 0.2f * e;
            num = expf(e - m) * inv;
        }
        int cnt = deg - base; if (cnt > 64) cnt = 64;
        for (int j = 0; j < cnt; j++) {
            float alpha = __shfl(num, j);
            int   src   = __shfl(s, j);
            float2 v = *(const float2*)&xw[(long)src * HID2 + lane * 2];
            a0 = fmaf(alpha, v.x, a0);
            a1 = fmaf(alpha, v.y, a1);
        }
    }
    out[(long)node * HID2 + lane * 2]     = selu_f(a0 + bias[lane * 2]);
    out[(long)node * HID2 + lane * 2 + 1] = selu_f(a1 + bias[lane * 2 + 1]);
}

// ---------------- pooling: one block per graph, binary search on sorted batch ----------------
__global__ __launch_bounds__(256) void pool_graph(
        const float* __restrict__ h, const int* __restrict__ batch,
        float* __restrict__ pooled) {
    int g = blockIdx.x;
    int lo = 0, hi = N_NODES;
    while (lo < hi) { int mid = (lo + hi) >> 1; if (batch[mid] < g) lo = mid + 1; else hi = mid; }
    int start = lo;
    lo = start; hi = N_NODES;
    while (lo < hi) { int mid = (lo + hi) >> 1; if (batch[mid] < g + 1) lo = mid + 1; else hi = mid; }
    int end = lo;

    int f = threadIdx.x & 127, half = threadIdx.x >> 7;
    float acc = 0.f;
    for (int n = start + half; n < end; n += 2) acc += h[(long)n * HID2 + f];
    __shared__ float part[HID2];
    if (half == 0) part[f] = acc;
    __syncthreads();
    if (half == 1) {
        float tot = part[f] + acc;
        float c = (float)(end - start);
        c = c > 1.f ? c : 1.f;
        pooled[g * HID2 + f] = selu_f(tot / c);
    }
}

// ---------------- head ----------------
__global__ void fc1_k(const float* __restrict__ pooled, const float* __restrict__ w,
                      const float* __restrict__ b, float* __restrict__ g) {
    __shared__ float row[HID2];
    int gi = blockIdx.x, j = threadIdx.x;   // 64 threads
    row[j] = pooled[gi * HID2 + j];
    row[j + 64] = pooled[gi * HID2 + 64 + j];
    __syncthreads();
    float acc = b[j];
#pragma unroll
    for (int k = 0; k < HID2; k++) acc = fmaf(row[k], w[k * NHID + j], acc);
    g[gi * NHID + j] = selu_f(acc);
}

__global__ void fc2_k(const float* __restrict__ g, const float* __restrict__ w,
                      const float* __restrict__ b, float* __restrict__ out) {
    int gi = blockIdx.x * blockDim.x + threadIdx.x;
    if (gi >= N_GRAPHS) return;
    float l0 = b[0], l1 = b[1];
#pragma unroll
    for (int k = 0; k < NHID; k++) {
        float v = g[gi * NHID + k];
        l0 = fmaf(v, w[k * 2 + 0], l0);
        l1 = fmaf(v, w[k * 2 + 1], l1);
    }
    float m = fmaxf(l0, l1);
    float lse = m + logf(expf(l0 - m) + expf(l1 - m));
    out[gi * 2 + 0] = l0 - lse;
    out[gi * 2 + 1] = l1 - lse;
}

extern "C" void kernel_launch(void* const* d_in, const int* in_sizes, int n_in,
                              void* d_out, int out_size, void* d_ws, size_t ws_size,
                              hipStream_t stream) {
    const float* x     = (const float*)d_in[0];
    const int*   ei    = (const int*)d_in[1];
    const int*   batch = (const int*)d_in[2];
    const float* W1    = (const float*)d_in[3];
    const float* as1   = (const float*)d_in[4];
    const float* ad1   = (const float*)d_in[5];
    const float* b1    = (const float*)d_in[6];
    const float* W2    = (const float*)d_in[7];
    const float* as2   = (const float*)d_in[8];
    const float* ad2   = (const float*)d_in[9];
    const float* b2    = (const float*)d_in[10];
    const float* fc1w  = (const float*)d_in[11];
    const float* fc1b  = (const float*)d_in[12];
    const float* fc2w  = (const float*)d_in[13];
    const float* fc2b  = (const float*)d_in[14];
    float* out = (float*)d_out;

    // workspace layout
    float* ws = (float*)d_ws;
    const long NH = (long)N_NODES * HID2;        // 6.4M
    float*    B0      = ws;                      // xw (layer1 then layer2)
    float*    B1      = B0 + NH;                 // h1
    float*    B2      = B1 + NH;                 // h2
    float*    e_src   = B2 + NH;
    float*    e_dst   = e_src + N_NODES;
    unsigned* deg     = (unsigned*)(e_dst + N_NODES);   // also cursor
    unsigned* row_ptr = deg + N_NODES;                  // N_NODES+1
    unsigned* csr_src = row_ptr + N_NODES + 1;          // E_TOT
    float*    pooled  = (float*)(csr_src + E_TOT);
    float*    g       = pooled + N_GRAPHS * HID2;
    unsigned short* Wt1 = (unsigned short*)(g + N_GRAPHS * NHID);  // 128x768 bf16
    unsigned short* Wt2 = Wt1 + 128 * IN_F;                        // 128x128 bf16

    const int TB = 256;
    const int gNode = (N_NODES + TB - 1) / TB;
    const int gEdge = (N_EDGES + TB - 1) / TB;
    const int gGemm = (N_NODES + 63) / 64;
    const int gAgg  = (N_NODES + 3) / 4;

    // weight convert+transpose (tiny)
    wcvt<<<(128 * IN_F + TB - 1) / TB, TB, 0, stream>>>(W1, Wt1, IN_F);
    wcvt<<<(128 * HID2 + TB - 1) / TB, TB, 0, stream>>>(W2, Wt2, HID2);

    // CSR build (shared by both layers)
    deg_init<<<gNode, TB, 0, stream>>>(deg);
    deg_hist<<<gEdge, TB, 0, stream>>>(ei, deg);
    scan_deg<<<gNode, TB, 0, stream>>>(deg, row_ptr);
    csr_seed<<<gNode, TB, 0, stream>>>(row_ptr, deg, csr_src);   // deg reused as cursor
    csr_scatter<<<gEdge, TB, 0, stream>>>(ei, deg, csr_src);

    // ---- layer 1 ----
    gemm_mfma<<<gGemm, 256, 0, stream>>>(x, Wt1, B0, N_NODES, IN_F);
    node_e<<<gNode, TB, 0, stream>>>(B0, as1, ad1, e_src, e_dst);
    gat_agg<<<gAgg, 256, 0, stream>>>(row_ptr, csr_src, e_src, e_dst, B0, b1, B1);

    // ---- layer 2 ----
    gemm_mfma<<<gGemm, 256, 0, stream>>>(B1, Wt2, B0, N_NODES, HID2);
    node_e<<<gNode, TB, 0, stream>>>(B0, as2, ad2, e_src, e_dst);
    gat_agg<<<gAgg, 256, 0, stream>>>(row_ptr, csr_src, e_src, e_dst, B0, b2, B2);

    // ---- pool + head ----
    pool_graph<<<N_GRAPHS, 256, 0, stream>>>(B2, batch, pooled);
    fc1_k<<<N_GRAPHS, NHID, 0, stream>>>(pooled, fc1w, fc1b, g);
    fc2_k<<<1, 128, 0, stream>>>(g, fc2w, fc2b, out);
}

// Round 5
// 591.438 us; speedup vs baseline: 3.2697x; 1.0635x over previous
//
#include <hip/hip_runtime.h>
#include <math.h>

#define N_NODES  50000
#define N_EDGES  800000
#define E_TOT    (N_EDGES + N_NODES)   // 850000 incl self loops
#define N_GRAPHS 128
#define IN_F     768
#define HID2     128
#define NHID     64

typedef __attribute__((ext_vector_type(8))) short bf16x8;
typedef __attribute__((ext_vector_type(4))) float f32x4;
typedef __attribute__((ext_vector_type(4))) unsigned short us4;

__device__ __forceinline__ float selu_f(float x) {
    const float alpha = 1.6732632423543772f;
    const float scale = 1.0507009873554805f;
    return scale * (x > 0.f ? x : alpha * (expf(x) - 1.f));
}

// round-to-nearest-even fp32 -> bf16
__device__ __forceinline__ unsigned short f2bf(float f) {
    unsigned u = __float_as_uint(f);
    u += 0x7FFFu + ((u >> 16) & 1u);
    return (unsigned short)(u >> 16);
}

// ---------------- setup: zero deg + convert/transpose both weight matrices ----------------
__global__ void setup_k(const float* __restrict__ W1, const float* __restrict__ W2,
                        unsigned short* __restrict__ Wt1, unsigned short* __restrict__ Wt2,
                        unsigned* __restrict__ deg) {
    int i = blockIdx.x * blockDim.x + threadIdx.x;
    if (i < N_NODES) deg[i] = 0u;
    if (i < 128 * IN_F) {
        int n = i / IN_F, k = i - n * IN_F;
        Wt1[i] = f2bf(W1[(long)k * 128 + n]);
    }
    if (i < 128 * HID2) {
        int n = i >> 7, k = i & 127;
        Wt2[i] = f2bf(W2[(long)k * 128 + n]);
    }
}

// ---------------- GEMM: bf16 MFMA, M-tile 64, BK=64, register-prefetch pipeline ----------------
#define LDA2 72   // padded LDS row stride (bf16): 144 B; frag reads conflict-free
__global__ __launch_bounds__(256) void gemm_mfma(
        const float* __restrict__ A, const unsigned short* __restrict__ Bt,
        float* __restrict__ C, int M, int K) {
    __shared__ unsigned short As[64 * LDA2];    // 9.2 KB
    __shared__ unsigned short Bs[128 * LDA2];   // 18.4 KB
    const int tid  = threadIdx.x;
    const int row0 = blockIdx.x * 64;
    const int w    = tid >> 6;
    const int lane = tid & 63;
    const int quad = lane >> 4;
    const int l16  = lane & 15;
    const int m_off = (w & 1) * 32;   // wave covers 32 rows
    const int n_off = (w >> 1) * 64;  // x 64 cols

    f32x4 acc[2][4];
#pragma unroll
    for (int mi = 0; mi < 2; mi++)
#pragma unroll
        for (int ni = 0; ni < 4; ni++)
            acc[mi][ni] = (f32x4){0.f, 0.f, 0.f, 0.f};

    float4 aR[4];
    bf16x8 bR[4];
#pragma unroll
    for (int i = 0; i < 4; i++) {
        int p = tid + i * 256;
        int r = p >> 4, c4 = p & 15;       // 64 rows x 16 float4
        int gr = row0 + r;
        aR[i] = (gr < M) ? *(const float4*)&A[(long)gr * K + c4 * 4]
                         : make_float4(0.f, 0.f, 0.f, 0.f);
    }
#pragma unroll
    for (int i = 0; i < 4; i++) {
        int c = tid + i * 256;
        int n = c >> 3, koff = (c & 7) * 8;  // 128 rows x 8 chunks
        bR[i] = *(const bf16x8*)&Bt[(long)n * K + koff];
    }

    for (int k0 = 0; k0 < K; k0 += 64) {
#pragma unroll
        for (int i = 0; i < 4; i++) {
            int p = tid + i * 256;
            int r = p >> 4, c4 = p & 15;
            us4 o;
            o.x = f2bf(aR[i].x); o.y = f2bf(aR[i].y);
            o.z = f2bf(aR[i].z); o.w = f2bf(aR[i].w);
            *(us4*)&As[r * LDA2 + c4 * 4] = o;
        }
#pragma unroll
        for (int i = 0; i < 4; i++) {
            int c = tid + i * 256;
            int n = c >> 3, koff = (c & 7) * 8;
            *(bf16x8*)&Bs[n * LDA2 + koff] = bR[i];
        }
        __syncthreads();

        if (k0 + 64 < K) {
            int k1 = k0 + 64;
#pragma unroll
            for (int i = 0; i < 4; i++) {
                int p = tid + i * 256;
                int r = p >> 4, c4 = p & 15;
                int gr = row0 + r;
                aR[i] = (gr < M) ? *(const float4*)&A[(long)gr * K + k1 + c4 * 4]
                                 : make_float4(0.f, 0.f, 0.f, 0.f);
            }
#pragma unroll
            for (int i = 0; i < 4; i++) {
                int c = tid + i * 256;
                int n = c >> 3, koff = (c & 7) * 8;
                bR[i] = *(const bf16x8*)&Bt[(long)n * K + k1 + koff];
            }
        }

        bf16x8 af[2][2], bfr[2][4];
#pragma unroll
        for (int kk = 0; kk < 2; kk++) {
#pragma unroll
            for (int mi = 0; mi < 2; mi++)
                af[kk][mi] = *(const bf16x8*)&As[(m_off + mi * 16 + l16) * LDA2 + kk * 32 + quad * 8];
#pragma unroll
            for (int ni = 0; ni < 4; ni++)
                bfr[kk][ni] = *(const bf16x8*)&Bs[(n_off + ni * 16 + l16) * LDA2 + kk * 32 + quad * 8];
        }
#pragma unroll
        for (int kk = 0; kk < 2; kk++)
#pragma unroll
            for (int mi = 0; mi < 2; mi++)
#pragma unroll
                for (int ni = 0; ni < 4; ni++)
                    acc[mi][ni] = __builtin_amdgcn_mfma_f32_16x16x32_bf16(
                        af[kk][mi], bfr[kk][ni], acc[mi][ni], 0, 0, 0);
        __syncthreads();
    }

#pragma unroll
    for (int mi = 0; mi < 2; mi++)
#pragma unroll
        for (int r = 0; r < 4; r++) {
            int row = row0 + m_off + mi * 16 + quad * 4 + r;
            if (row < M) {
#pragma unroll
                for (int ni = 0; ni < 4; ni++)
                    C[(long)row * 128 + n_off + ni * 16 + l16] = acc[mi][ni][r];
            }
        }
}

// ---------------- attention logit halves ----------------
__global__ void node_e(const float* __restrict__ xw,
                       const float* __restrict__ a_s, const float* __restrict__ a_d,
                       float* __restrict__ e_src, float* __restrict__ e_dst) {
    int i = blockIdx.x * blockDim.x + threadIdx.x;
    if (i >= N_NODES) return;
    const float4* row = (const float4*)(xw + (long)i * HID2);
    float s = 0.f, d = 0.f;
#pragma unroll
    for (int j = 0; j < 32; j++) {
        float4 v = row[j];
        float4 as = ((const float4*)a_s)[j];
        float4 ad = ((const float4*)a_d)[j];
        s += v.x * as.x + v.y * as.y + v.z * as.z + v.w * as.w;
        d += v.x * ad.x + v.y * ad.y + v.z * ad.z + v.w * ad.w;
    }
    e_src[i] = s;
    e_dst[i] = d;
}

// ---------------- CSR build ----------------
__global__ void deg_hist(const int* __restrict__ ei, unsigned* __restrict__ deg) {
    int e = blockIdx.x * blockDim.x + threadIdx.x;
    if (e < N_EDGES) atomicAdd(&deg[ei[N_EDGES + e]], 1u);
}

// exclusive scan of (deg+1) -> row_ptr, fused with self-loop seed + cursor init.
__global__ __launch_bounds__(256) void scan_seed(const unsigned* __restrict__ deg,
                                                 unsigned* __restrict__ row_ptr,
                                                 unsigned* __restrict__ cursor,
                                                 unsigned* __restrict__ csr_src) {
    __shared__ unsigned psum_s[4];
    __shared__ unsigned wsum[4];
    int tid = threadIdx.x;
    int wid = tid >> 6, lane = tid & 63;
    int chunk0 = blockIdx.x * 256;

    unsigned psum = 0;
    for (int i = tid; i < chunk0; i += 256) psum += deg[i] + 1u;
    for (int o = 32; o; o >>= 1) psum += __shfl_xor(psum, o);
    if (lane == 0) psum_s[wid] = psum;

    int i = chunk0 + tid;
    unsigned v = (i < N_NODES) ? deg[i] + 1u : 0u;
    unsigned x = v;
    for (int o = 1; o < 64; o <<= 1) {
        unsigned y = __shfl_up(x, o);
        if (lane >= o) x += y;
    }
    if (lane == 63) wsum[wid] = x;
    __syncthreads();
    unsigned base = psum_s[0] + psum_s[1] + psum_s[2] + psum_s[3];
    unsigned wbase = 0;
    for (int k = 0; k < wid; k++) wbase += wsum[k];
    if (i < N_NODES) {
        unsigned rp = base + wbase + x - v;
        row_ptr[i] = rp;
        csr_src[rp] = (unsigned)i;   // self-loop first
        cursor[i] = rp + 1;
        if (i == N_NODES - 1) row_ptr[N_NODES] = rp + v;
    }
}

__global__ void csr_scatter(const int* __restrict__ ei,
                            unsigned* __restrict__ cursor, unsigned* __restrict__ csr_src) {
    int e = blockIdx.x * blockDim.x + threadIdx.x;
    if (e >= N_EDGES) return;
    int d = ei[N_EDGES + e];
    unsigned p = atomicAdd(&cursor[d], 1u);
    csr_src[p] = (unsigned)ei[e];
}

// ---------------- fused GAT tail: single edge pass, late normalization ----------------
// out[n] = (sum_e num_e * xw[src_e]) / (sum_e num_e); no segment-max needed (|e| ~< 8).
// one wave per dst node; lane holds features 2*lane, 2*lane+1
__global__ __launch_bounds__(256) void gat_agg(
        const unsigned* __restrict__ row_ptr, const unsigned* __restrict__ csr_src,
        const float* __restrict__ e_src, const float* __restrict__ e_dst,
        const float* __restrict__ xw, const float* __restrict__ bias,
        float* __restrict__ out) {
    __shared__ float2 buf[4][64];     // (num, src-bits) per wave
    int wv = threadIdx.x >> 6;
    int node = blockIdx.x * 4 + wv;
    if (node >= N_NODES) return;
    int lane = threadIdx.x & 63;
    unsigned beg = row_ptr[node], end = row_ptr[node + 1];
    int deg = (int)(end - beg);
    float ed = e_dst[node];

    float a0 = 0.f, a1 = 0.f, den = 0.f;
    for (int base = 0; base < deg; base += 64) {
        int i = base + lane;
        float num = 0.f;
        unsigned s = 0u;
        if (i < deg) {
            s = csr_src[beg + i];
            float e = e_src[s] + ed;
            e = e > 0.f ? e : 0.2f * e;
            num = __expf(e);
            den += num;
        }
        float2 pk; pk.x = num; pk.y = __uint_as_float(s);
        buf[wv][lane] = pk;

        int cnt = deg - base; if (cnt > 64) cnt = 64;
        int j = 0;
        for (; j + 4 <= cnt; j += 4) {
            float2 p0 = buf[wv][j + 0];
            float2 p1 = buf[wv][j + 1];
            float2 p2 = buf[wv][j + 2];
            float2 p3 = buf[wv][j + 3];
            float2 v0 = *(const float2*)&xw[(long)__float_as_uint(p0.y) * HID2 + lane * 2];
            float2 v1 = *(const float2*)&xw[(long)__float_as_uint(p1.y) * HID2 + lane * 2];
            float2 v2 = *(const float2*)&xw[(long)__float_as_uint(p2.y) * HID2 + lane * 2];
            float2 v3 = *(const float2*)&xw[(long)__float_as_uint(p3.y) * HID2 + lane * 2];
            a0 = fmaf(p0.x, v0.x, a0); a1 = fmaf(p0.x, v0.y, a1);
            a0 = fmaf(p1.x, v1.x, a0); a1 = fmaf(p1.x, v1.y, a1);
            a0 = fmaf(p2.x, v2.x, a0); a1 = fmaf(p2.x, v2.y, a1);
            a0 = fmaf(p3.x, v3.x, a0); a1 = fmaf(p3.x, v3.y, a1);
        }
        for (; j < cnt; j++) {
            float2 p = buf[wv][j];
            float2 v = *(const float2*)&xw[(long)__float_as_uint(p.y) * HID2 + lane * 2];
            a0 = fmaf(p.x, v.x, a0); a1 = fmaf(p.x, v.y, a1);
        }
    }
    for (int o = 32; o; o >>= 1) den += __shfl_xor(den, o);
    float inv = 1.f / den;
    out[(long)node * HID2 + lane * 2]     = selu_f(fmaf(a0, inv, bias[lane * 2]));
    out[(long)node * HID2 + lane * 2 + 1] = selu_f(fmaf(a1, inv, bias[lane * 2 + 1]));
}

// ---------------- pooling: one block per graph, binary search on sorted batch ----------------
__global__ __launch_bounds__(256) void pool_graph(
        const float* __restrict__ h, const int* __restrict__ batch,
        float* __restrict__ pooled) {
    int g = blockIdx.x;
    int lo = 0, hi = N_NODES;
    while (lo < hi) { int mid = (lo + hi) >> 1; if (batch[mid] < g) lo = mid + 1; else hi = mid; }
    int start = lo;
    lo = start; hi = N_NODES;
    while (lo < hi) { int mid = (lo + hi) >> 1; if (batch[mid] < g + 1) lo = mid + 1; else hi = mid; }
    int end = lo;

    int f = threadIdx.x & 127, half = threadIdx.x >> 7;
    float acc = 0.f;
    for (int n = start + half; n < end; n += 2) acc += h[(long)n * HID2 + f];
    __shared__ float part[HID2];
    if (half == 0) part[f] = acc;
    __syncthreads();
    if (half == 1) {
        float tot = part[f] + acc;
        float c = (float)(end - start);
        c = c > 1.f ? c : 1.f;
        pooled[g * HID2 + f] = selu_f(tot / c);
    }
}

// ---------------- head ----------------
__global__ void fc1_k(const float* __restrict__ pooled, const float* __restrict__ w,
                      const float* __restrict__ b, float* __restrict__ g) {
    __shared__ float row[HID2];
    int gi = blockIdx.x, j = threadIdx.x;   // 64 threads
    row[j] = pooled[gi * HID2 + j];
    row[j + 64] = pooled[gi * HID2 + 64 + j];
    __syncthreads();
    float acc = b[j];
#pragma unroll
    for (int k = 0; k < HID2; k++) acc = fmaf(row[k], w[k * NHID + j], acc);
    g[gi * NHID + j] = selu_f(acc);
}

__global__ void fc2_k(const float* __restrict__ g, const float* __restrict__ w,
                      const float* __restrict__ b, float* __restrict__ out) {
    int gi = blockIdx.x * blockDim.x + threadIdx.x;
    if (gi >= N_GRAPHS) return;
    float l0 = b[0], l1 = b[1];
#pragma unroll
    for (int k = 0; k < NHID; k++) {
        float v = g[gi * NHID + k];
        l0 = fmaf(v, w[k * 2 + 0], l0);
        l1 = fmaf(v, w[k * 2 + 1], l1);
    }
    float m = fmaxf(l0, l1);
    float lse = m + logf(expf(l0 - m) + expf(l1 - m));
    out[gi * 2 + 0] = l0 - lse;
    out[gi * 2 + 1] = l1 - lse;
}

extern "C" void kernel_launch(void* const* d_in, const int* in_sizes, int n_in,
                              void* d_out, int out_size, void* d_ws, size_t ws_size,
                              hipStream_t stream) {
    const float* x     = (const float*)d_in[0];
    const int*   ei    = (const int*)d_in[1];
    const int*   batch = (const int*)d_in[2];
    const float* W1    = (const float*)d_in[3];
    const float* as1   = (const float*)d_in[4];
    const float* ad1   = (const float*)d_in[5];
    const float* b1    = (const float*)d_in[6];
    const float* W2    = (const float*)d_in[7];
    const float* as2   = (const float*)d_in[8];
    const float* ad2   = (const float*)d_in[9];
    const float* b2    = (const float*)d_in[10];
    const float* fc1w  = (const float*)d_in[11];
    const float* fc1b  = (const float*)d_in[12];
    const float* fc2w  = (const float*)d_in[13];
    const float* fc2b  = (const float*)d_in[14];
    float* out = (float*)d_out;

    // workspace layout
    float* ws = (float*)d_ws;
    const long NH = (long)N_NODES * HID2;        // 6.4M
    float*    B0      = ws;                      // xw (layer1 then layer2)
    float*    B1      = B0 + NH;                 // h1
    float*    B2      = B1 + NH;                 // h2
    float*    e_src   = B2 + NH;
    float*    e_dst   = e_src + N_NODES;
    unsigned* deg     = (unsigned*)(e_dst + N_NODES);
    unsigned* cursor  = deg + N_NODES;
    unsigned* row_ptr = cursor + N_NODES;               // N_NODES+1
    unsigned* csr_src = row_ptr + N_NODES + 1;          // E_TOT
    float*    pooled  = (float*)(csr_src + E_TOT);
    float*    g       = pooled + N_GRAPHS * HID2;
    unsigned short* Wt1 = (unsigned short*)(g + N_GRAPHS * NHID);  // 128x768 bf16
    unsigned short* Wt2 = Wt1 + 128 * IN_F;                        // 128x128 bf16

    const int TB = 256;
    const int gNode = (N_NODES + TB - 1) / TB;
    const int gEdge = (N_EDGES + TB - 1) / TB;
    const int gGemm = (N_NODES + 63) / 64;
    const int gAgg  = (N_NODES + 3) / 4;

    // setup (zero deg + both weight converts) + CSR build
    setup_k<<<(128 * IN_F + TB - 1) / TB, TB, 0, stream>>>(W1, W2, Wt1, Wt2, deg);
    deg_hist<<<gEdge, TB, 0, stream>>>(ei, deg);
    scan_seed<<<gNode, TB, 0, stream>>>(deg, row_ptr, cursor, csr_src);
    csr_scatter<<<gEdge, TB, 0, stream>>>(ei, cursor, csr_src);

    // ---- layer 1 ----
    gemm_mfma<<<gGemm, 256, 0, stream>>>(x, Wt1, B0, N_NODES, IN_F);
    node_e<<<gNode, TB, 0, stream>>>(B0, as1, ad1, e_src, e_dst);
    gat_agg<<<gAgg, 256, 0, stream>>>(row_ptr, csr_src, e_src, e_dst, B0, b1, B1);

    // ---- layer 2 ----
    gemm_mfma<<<gGemm, 256, 0, stream>>>(B1, Wt2, B0, N_NODES, HID2);
    node_e<<<gNode, TB, 0, stream>>>(B0, as2, ad2, e_src, e_dst);
    gat_agg<<<gAgg, 256, 0, stream>>>(row_ptr, csr_src, e_src, e_dst, B0, b2, B2);

    // ---- pool + head ----
    pool_graph<<<N_GRAPHS, 256, 0, stream>>>(B2, batch, pooled);
    fc1_k<<<N_GRAPHS, NHID, 0, stream>>>(pooled, fc1w, fc1b, g);
    fc2_k<<<1, 128, 0, stream>>>(g, fc2w, fc2b, out);
}

// Round 6
// 537.016 us; speedup vs baseline: 3.6010x; 1.1013x over previous
//
#include <hip/hip_runtime.h>
#include <math.h>

#define N_NODES  50000
#define N_EDGES  800000
#define E_TOT    (N_EDGES + N_NODES)   // 850000 incl self loops
#define N_GRAPHS 128
#define IN_F     768
#define HID2     128
#define NHID     64

typedef __attribute__((ext_vector_type(8))) short bf16x8;
typedef __attribute__((ext_vector_type(4))) float f32x4;
typedef __attribute__((ext_vector_type(4))) unsigned short us4;

__device__ __forceinline__ float selu_f(float x) {
    const float alpha = 1.6732632423543772f;
    const float scale = 1.0507009873554805f;
    return scale * (x > 0.f ? x : alpha * (expf(x) - 1.f));
}

// round-to-nearest-even fp32 -> bf16
__device__ __forceinline__ unsigned short f2bf(float f) {
    unsigned u = __float_as_uint(f);
    u += 0x7FFFu + ((u >> 16) & 1u);
    return (unsigned short)(u >> 16);
}
__device__ __forceinline__ float bf2f(unsigned short b) {
    return __uint_as_float(((unsigned)b) << 16);
}

// ---------------- setup: zero deg + convert/transpose both weight matrices ----------------
__global__ void setup_k(const float* __restrict__ W1, const float* __restrict__ W2,
                        unsigned short* __restrict__ Wt1, unsigned short* __restrict__ Wt2,
                        unsigned* __restrict__ deg) {
    int i = blockIdx.x * blockDim.x + threadIdx.x;
    if (i < N_NODES) deg[i] = 0u;
    if (i < 128 * IN_F) {
        int n = i / IN_F, k = i - n * IN_F;
        Wt1[i] = f2bf(W1[(long)k * 128 + n]);
    }
    if (i < 128 * HID2) {
        int n = i >> 7, k = i & 127;
        Wt2[i] = f2bf(W2[(long)k * 128 + n]);
    }
}

// ---------------- GEMM: bf16 MFMA, M-tile 64, BK=64, register-prefetch pipeline ----------------
// ABF16: A is bf16 row-major (pure copy staging). OUTBF16: C written as bf16.
#define LDA2 72   // padded LDS row stride (bf16): 144 B; frag reads conflict-free
template<bool ABF16, bool OUTBF16>
__global__ __launch_bounds__(256) void gemm_mfma(
        const void* __restrict__ Av, const unsigned short* __restrict__ Bt,
        void* __restrict__ Cv, int M, int K) {
    __shared__ unsigned short As[64 * LDA2];    // 9.2 KB
    __shared__ unsigned short Bs[128 * LDA2];   // 18.4 KB
    const float* Af = (const float*)Av;
    const unsigned short* Ab = (const unsigned short*)Av;
    const int tid  = threadIdx.x;
    const int row0 = blockIdx.x * 64;
    const int w    = tid >> 6;
    const int lane = tid & 63;
    const int quad = lane >> 4;
    const int l16  = lane & 15;
    const int m_off = (w & 1) * 32;   // wave covers 32 rows
    const int n_off = (w >> 1) * 64;  // x 64 cols

    f32x4 acc[2][4];
#pragma unroll
    for (int mi = 0; mi < 2; mi++)
#pragma unroll
        for (int ni = 0; ni < 4; ni++)
            acc[mi][ni] = (f32x4){0.f, 0.f, 0.f, 0.f};

    float4 aR[4];
    bf16x8 aRb[2];
    bf16x8 bR[4];
    // prologue: tile 0 -> regs
    if (ABF16) {
#pragma unroll
        for (int i = 0; i < 2; i++) {
            int p = tid + i * 256;           // 512 chunks: 64 rows x 8 (8-bf16) chunks
            int r = p >> 3, c8 = p & 7;
            int gr = row0 + r;
            aRb[i] = (gr < M) ? *(const bf16x8*)&Ab[(long)gr * K + c8 * 8]
                              : (bf16x8){0,0,0,0,0,0,0,0};
        }
    } else {
#pragma unroll
        for (int i = 0; i < 4; i++) {
            int p = tid + i * 256;           // 1024 slots: 64 rows x 16 float4
            int r = p >> 4, c4 = p & 15;
            int gr = row0 + r;
            aR[i] = (gr < M) ? *(const float4*)&Af[(long)gr * K + c4 * 4]
                             : make_float4(0.f, 0.f, 0.f, 0.f);
        }
    }
#pragma unroll
    for (int i = 0; i < 4; i++) {
        int c = tid + i * 256;
        int n = c >> 3, koff = (c & 7) * 8;  // 128 rows x 8 chunks
        bR[i] = *(const bf16x8*)&Bt[(long)n * K + koff];
    }

    for (int k0 = 0; k0 < K; k0 += 64) {
        // store current tile regs -> LDS
        if (ABF16) {
#pragma unroll
            for (int i = 0; i < 2; i++) {
                int p = tid + i * 256;
                int r = p >> 3, c8 = p & 7;
                *(bf16x8*)&As[r * LDA2 + c8 * 8] = aRb[i];
            }
        } else {
#pragma unroll
            for (int i = 0; i < 4; i++) {
                int p = tid + i * 256;
                int r = p >> 4, c4 = p & 15;
                us4 o;
                o.x = f2bf(aR[i].x); o.y = f2bf(aR[i].y);
                o.z = f2bf(aR[i].z); o.w = f2bf(aR[i].w);
                *(us4*)&As[r * LDA2 + c4 * 4] = o;
            }
        }
#pragma unroll
        for (int i = 0; i < 4; i++) {
            int c = tid + i * 256;
            int n = c >> 3, koff = (c & 7) * 8;
            *(bf16x8*)&Bs[n * LDA2 + koff] = bR[i];
        }
        __syncthreads();

        // prefetch next tile (latency overlaps MFMA below)
        if (k0 + 64 < K) {
            int k1 = k0 + 64;
            if (ABF16) {
#pragma unroll
                for (int i = 0; i < 2; i++) {
                    int p = tid + i * 256;
                    int r = p >> 3, c8 = p & 7;
                    int gr = row0 + r;
                    aRb[i] = (gr < M) ? *(const bf16x8*)&Ab[(long)gr * K + k1 + c8 * 8]
                                      : (bf16x8){0,0,0,0,0,0,0,0};
                }
            } else {
#pragma unroll
                for (int i = 0; i < 4; i++) {
                    int p = tid + i * 256;
                    int r = p >> 4, c4 = p & 15;
                    int gr = row0 + r;
                    aR[i] = (gr < M) ? *(const float4*)&Af[(long)gr * K + k1 + c4 * 4]
                                     : make_float4(0.f, 0.f, 0.f, 0.f);
                }
            }
#pragma unroll
            for (int i = 0; i < 4; i++) {
                int c = tid + i * 256;
                int n = c >> 3, koff = (c & 7) * 8;
                bR[i] = *(const bf16x8*)&Bt[(long)n * K + k1 + koff];
            }
        }

        bf16x8 af[2][2], bfr[2][4];
#pragma unroll
        for (int kk = 0; kk < 2; kk++) {
#pragma unroll
            for (int mi = 0; mi < 2; mi++)
                af[kk][mi] = *(const bf16x8*)&As[(m_off + mi * 16 + l16) * LDA2 + kk * 32 + quad * 8];
#pragma unroll
            for (int ni = 0; ni < 4; ni++)
                bfr[kk][ni] = *(const bf16x8*)&Bs[(n_off + ni * 16 + l16) * LDA2 + kk * 32 + quad * 8];
        }
#pragma unroll
        for (int kk = 0; kk < 2; kk++)
#pragma unroll
            for (int mi = 0; mi < 2; mi++)
#pragma unroll
                for (int ni = 0; ni < 4; ni++)
                    acc[mi][ni] = __builtin_amdgcn_mfma_f32_16x16x32_bf16(
                        af[kk][mi], bfr[kk][ni], acc[mi][ni], 0, 0, 0);
        __syncthreads();
    }

    // epilogue: D row = m_off+mi*16+quad*4+r, col = n_off+ni*16+l16
#pragma unroll
    for (int mi = 0; mi < 2; mi++)
#pragma unroll
        for (int r = 0; r < 4; r++) {
            int row = row0 + m_off + mi * 16 + quad * 4 + r;
            if (row < M) {
                if (OUTBF16) {
                    unsigned short* C16 = (unsigned short*)Cv;
#pragma unroll
                    for (int ni = 0; ni < 4; ni++)
                        C16[(long)row * 128 + n_off + ni * 16 + l16] = f2bf(acc[mi][ni][r]);
                } else {
                    float* Cf = (float*)Cv;
#pragma unroll
                    for (int ni = 0; ni < 4; ni++)
                        Cf[(long)row * 128 + n_off + ni * 16 + l16] = acc[mi][ni][r];
                }
            }
        }
}

// ---------------- attention logit halves (bf16 xw) ----------------
__global__ void node_e(const unsigned short* __restrict__ xw,
                       const float* __restrict__ a_s, const float* __restrict__ a_d,
                       float* __restrict__ e_src, float* __restrict__ e_dst) {
    int i = blockIdx.x * blockDim.x + threadIdx.x;
    if (i >= N_NODES) return;
    const bf16x8* row = (const bf16x8*)(xw + (long)i * HID2);
    float s = 0.f, d = 0.f;
#pragma unroll
    for (int j = 0; j < 16; j++) {
        bf16x8 v = row[j];
#pragma unroll
        for (int e = 0; e < 8; e++) {
            float f = bf2f((unsigned short)v[e]);
            s = fmaf(f, a_s[j * 8 + e], s);
            d = fmaf(f, a_d[j * 8 + e], d);
        }
    }
    e_src[i] = s;
    e_dst[i] = d;
}

// ---------------- CSR build ----------------
__global__ void deg_hist(const int* __restrict__ ei, unsigned* __restrict__ deg) {
    int e = blockIdx.x * blockDim.x + threadIdx.x;
    if (e < N_EDGES) atomicAdd(&deg[ei[N_EDGES + e]], 1u);
}

// exclusive scan of (deg+1) -> row_ptr, fused with self-loop seed + cursor init.
__global__ __launch_bounds__(256) void scan_seed(const unsigned* __restrict__ deg,
                                                 unsigned* __restrict__ row_ptr,
                                                 unsigned* __restrict__ cursor,
                                                 unsigned* __restrict__ csr_src) {
    __shared__ unsigned psum_s[4];
    __shared__ unsigned wsum[4];
    int tid = threadIdx.x;
    int wid = tid >> 6, lane = tid & 63;
    int chunk0 = blockIdx.x * 256;

    unsigned psum = 0;
    for (int i = tid; i < chunk0; i += 256) psum += deg[i] + 1u;
    for (int o = 32; o; o >>= 1) psum += __shfl_xor(psum, o);
    if (lane == 0) psum_s[wid] = psum;

    int i = chunk0 + tid;
    unsigned v = (i < N_NODES) ? deg[i] + 1u : 0u;
    unsigned x = v;
    for (int o = 1; o < 64; o <<= 1) {
        unsigned y = __shfl_up(x, o);
        if (lane >= o) x += y;
    }
    if (lane == 63) wsum[wid] = x;
    __syncthreads();
    unsigned base = psum_s[0] + psum_s[1] + psum_s[2] + psum_s[3];
    unsigned wbase = 0;
    for (int k = 0; k < wid; k++) wbase += wsum[k];
    if (i < N_NODES) {
        unsigned rp = base + wbase + x - v;
        row_ptr[i] = rp;
        csr_src[rp] = (unsigned)i;   // self-loop first
        cursor[i] = rp + 1;
        if (i == N_NODES - 1) row_ptr[N_NODES] = rp + v;
    }
}

__global__ void csr_scatter(const int* __restrict__ ei,
                            unsigned* __restrict__ cursor, unsigned* __restrict__ csr_src) {
    int e = blockIdx.x * blockDim.x + threadIdx.x;
    if (e >= N_EDGES) return;
    int d = ei[N_EDGES + e];
    unsigned p = atomicAdd(&cursor[d], 1u);
    csr_src[p] = (unsigned)ei[e];
}

// ---------------- fused GAT tail: single edge pass, late normalization ----------------
// out[n] = (sum_e num_e * xw[src_e]) / (sum_e num_e); no segment-max needed (|e| ~< 8).
// one wave per dst node; lane holds features 2*lane, 2*lane+1 (bf16-pair gather = 4B/lane)
template<bool OUTBF16>
__global__ __launch_bounds__(256) void gat_agg(
        const unsigned* __restrict__ row_ptr, const unsigned* __restrict__ csr_src,
        const float* __restrict__ e_src, const float* __restrict__ e_dst,
        const unsigned short* __restrict__ xw, const float* __restrict__ bias,
        void* __restrict__ outv) {
    __shared__ float2 buf[4][64];     // (num, src-bits) per wave
    int wv = threadIdx.x >> 6;
    int node = blockIdx.x * 4 + wv;
    if (node >= N_NODES) return;
    int lane = threadIdx.x & 63;
    unsigned beg = row_ptr[node], end = row_ptr[node + 1];
    int deg = (int)(end - beg);
    float ed = e_dst[node];

    float a0 = 0.f, a1 = 0.f, den = 0.f;
    for (int base = 0; base < deg; base += 64) {
        int i = base + lane;
        float num = 0.f;
        unsigned s = 0u;
        if (i < deg) {
            s = csr_src[beg + i];
            float e = e_src[s] + ed;
            e = e > 0.f ? e : 0.2f * e;
            num = __expf(e);
            den += num;
        }
        float2 pk; pk.x = num; pk.y = __uint_as_float(s);
        buf[wv][lane] = pk;

        int cnt = deg - base; if (cnt > 64) cnt = 64;
        int j = 0;
        for (; j + 4 <= cnt; j += 4) {
            float2 p0 = buf[wv][j + 0];
            float2 p1 = buf[wv][j + 1];
            float2 p2 = buf[wv][j + 2];
            float2 p3 = buf[wv][j + 3];
            unsigned q0 = *(const unsigned*)&xw[(long)__float_as_uint(p0.y) * HID2 + lane * 2];
            unsigned q1 = *(const unsigned*)&xw[(long)__float_as_uint(p1.y) * HID2 + lane * 2];
            unsigned q2 = *(const unsigned*)&xw[(long)__float_as_uint(p2.y) * HID2 + lane * 2];
            unsigned q3 = *(const unsigned*)&xw[(long)__float_as_uint(p3.y) * HID2 + lane * 2];
            a0 = fmaf(p0.x, __uint_as_float(q0 << 16), a0);
            a1 = fmaf(p0.x, __uint_as_float(q0 & 0xffff0000u), a1);
            a0 = fmaf(p1.x, __uint_as_float(q1 << 16), a0);
            a1 = fmaf(p1.x, __uint_as_float(q1 & 0xffff0000u), a1);
            a0 = fmaf(p2.x, __uint_as_float(q2 << 16), a0);
            a1 = fmaf(p2.x, __uint_as_float(q2 & 0xffff0000u), a1);
            a0 = fmaf(p3.x, __uint_as_float(q3 << 16), a0);
            a1 = fmaf(p3.x, __uint_as_float(q3 & 0xffff0000u), a1);
        }
        for (; j < cnt; j++) {
            float2 p = buf[wv][j];
            unsigned q = *(const unsigned*)&xw[(long)__float_as_uint(p.y) * HID2 + lane * 2];
            a0 = fmaf(p.x, __uint_as_float(q << 16), a0);
            a1 = fmaf(p.x, __uint_as_float(q & 0xffff0000u), a1);
        }
    }
    for (int o = 32; o; o >>= 1) den += __shfl_xor(den, o);
    float inv = 1.f / den;
    float v0 = selu_f(fmaf(a0, inv, bias[lane * 2]));
    float v1 = selu_f(fmaf(a1, inv, bias[lane * 2 + 1]));
    if (OUTBF16) {
        unsigned* ob = (unsigned*)outv;
        ob[(long)node * 64 + lane] = ((unsigned)f2bf(v1) << 16) | (unsigned)f2bf(v0);
    } else {
        float* of = (float*)outv;
        of[(long)node * HID2 + lane * 2]     = v0;
        of[(long)node * HID2 + lane * 2 + 1] = v1;
    }
}

// ---------------- pooling: one block per graph, binary search on sorted batch ----------------
__global__ __launch_bounds__(256) void pool_graph(
        const float* __restrict__ h, const int* __restrict__ batch,
        float* __restrict__ pooled) {
    int g = blockIdx.x;
    int lo = 0, hi = N_NODES;
    while (lo < hi) { int mid = (lo + hi) >> 1; if (batch[mid] < g) lo = mid + 1; else hi = mid; }
    int start = lo;
    lo = start; hi = N_NODES;
    while (lo < hi) { int mid = (lo + hi) >> 1; if (batch[mid] < g + 1) lo = mid + 1; else hi = mid; }
    int end = lo;

    int f = threadIdx.x & 127, half = threadIdx.x >> 7;
    float acc = 0.f;
    for (int n = start + half; n < end; n += 2) acc += h[(long)n * HID2 + f];
    __shared__ float part[HID2];
    if (half == 0) part[f] = acc;
    __syncthreads();
    if (half == 1) {
        float tot = part[f] + acc;
        float c = (float)(end - start);
        c = c > 1.f ? c : 1.f;
        pooled[g * HID2 + f] = selu_f(tot / c);
    }
}

// ---------------- head ----------------
__global__ void fc1_k(const float* __restrict__ pooled, const float* __restrict__ w,
                      const float* __restrict__ b, float* __restrict__ g) {
    __shared__ float row[HID2];
    int gi = blockIdx.x, j = threadIdx.x;   // 64 threads
    row[j] = pooled[gi * HID2 + j];
    row[j + 64] = pooled[gi * HID2 + 64 + j];
    __syncthreads();
    float acc = b[j];
#pragma unroll
    for (int k = 0; k < HID2; k++) acc = fmaf(row[k], w[k * NHID + j], acc);
    g[gi * NHID + j] = selu_f(acc);
}

__global__ void fc2_k(const float* __restrict__ g, const float* __restrict__ w,
                      const float* __restrict__ b, float* __restrict__ out) {
    int gi = blockIdx.x * blockDim.x + threadIdx.x;
    if (gi >= N_GRAPHS) return;
    float l0 = b[0], l1 = b[1];
#pragma unroll
    for (int k = 0; k < NHID; k++) {
        float v = g[gi * NHID + k];
        l0 = fmaf(v, w[k * 2 + 0], l0);
        l1 = fmaf(v, w[k * 2 + 1], l1);
    }
    float m = fmaxf(l0, l1);
    float lse = m + logf(expf(l0 - m) + expf(l1 - m));
    out[gi * 2 + 0] = l0 - lse;
    out[gi * 2 + 1] = l1 - lse;
}

extern "C" void kernel_launch(void* const* d_in, const int* in_sizes, int n_in,
                              void* d_out, int out_size, void* d_ws, size_t ws_size,
                              hipStream_t stream) {
    const float* x     = (const float*)d_in[0];
    const int*   ei    = (const int*)d_in[1];
    const int*   batch = (const int*)d_in[2];
    const float* W1    = (const float*)d_in[3];
    const float* as1   = (const float*)d_in[4];
    const float* ad1   = (const float*)d_in[5];
    const float* b1    = (const float*)d_in[6];
    const float* W2    = (const float*)d_in[7];
    const float* as2   = (const float*)d_in[8];
    const float* ad2   = (const float*)d_in[9];
    const float* b2    = (const float*)d_in[10];
    const float* fc1w  = (const float*)d_in[11];
    const float* fc1b  = (const float*)d_in[12];
    const float* fc2w  = (const float*)d_in[13];
    const float* fc2b  = (const float*)d_in[14];
    float* out = (float*)d_out;

    // workspace layout
    const long NH = (long)N_NODES * HID2;        // 6.4M elems
    unsigned short* xwb = (unsigned short*)d_ws;         // NH bf16 (xw, layer1 then layer2)
    unsigned short* h1b = xwb + NH;                      // NH bf16 (h1)
    float*    B2      = (float*)(h1b + NH);              // NH f32 (h2, for pooling)
    float*    e_src   = B2 + NH;
    float*    e_dst   = e_src + N_NODES;
    unsigned* deg     = (unsigned*)(e_dst + N_NODES);
    unsigned* cursor  = deg + N_NODES;
    unsigned* row_ptr = cursor + N_NODES;               // N_NODES+1
    unsigned* csr_src = row_ptr + N_NODES + 1;          // E_TOT
    float*    pooled  = (float*)(csr_src + E_TOT);
    float*    g       = pooled + N_GRAPHS * HID2;
    unsigned short* Wt1 = (unsigned short*)(g + N_GRAPHS * NHID);  // 128x768 bf16
    unsigned short* Wt2 = Wt1 + 128 * IN_F;                        // 128x128 bf16

    const int TB = 256;
    const int gNode = (N_NODES + TB - 1) / TB;
    const int gEdge = (N_EDGES + TB - 1) / TB;
    const int gGemm = (N_NODES + 63) / 64;
    const int gAgg  = (N_NODES + 3) / 4;

    // setup (zero deg + both weight converts) + CSR build
    setup_k<<<(128 * IN_F + TB - 1) / TB, TB, 0, stream>>>(W1, W2, Wt1, Wt2, deg);
    deg_hist<<<gEdge, TB, 0, stream>>>(ei, deg);
    scan_seed<<<gNode, TB, 0, stream>>>(deg, row_ptr, cursor, csr_src);
    csr_scatter<<<gEdge, TB, 0, stream>>>(ei, cursor, csr_src);

    // ---- layer 1 ----
    gemm_mfma<false, true><<<gGemm, 256, 0, stream>>>(x, Wt1, xwb, N_NODES, IN_F);
    node_e<<<gNode, TB, 0, stream>>>(xwb, as1, ad1, e_src, e_dst);
    gat_agg<true><<<gAgg, 256, 0, stream>>>(row_ptr, csr_src, e_src, e_dst, xwb, b1, h1b);

    // ---- layer 2 ----
    gemm_mfma<true, true><<<gGemm, 256, 0, stream>>>(h1b, Wt2, xwb, N_NODES, HID2);
    node_e<<<gNode, TB, 0, stream>>>(xwb, as2, ad2, e_src, e_dst);
    gat_agg<false><<<gAgg, 256, 0, stream>>>(row_ptr, csr_src, e_src, e_dst, xwb, b2, B2);

    // ---- pool + head ----
    pool_graph<<<N_GRAPHS, 256, 0, stream>>>(B2, batch, pooled);
    fc1_k<<<N_GRAPHS, NHID, 0, stream>>>(pooled, fc1w, fc1b, g);
    fc2_k<<<1, 128, 0, stream>>>(g, fc2w, fc2b, out);
}

// Round 7
// 521.621 us; speedup vs baseline: 3.7073x; 1.0295x over previous
//
#include <hip/hip_runtime.h>
#include <math.h>

#define N_NODES  50000
#define N_EDGES  800000
#define E_TOT    (N_EDGES + N_NODES)   // 850000 incl self loops
#define N_GRAPHS 128
#define IN_F     768
#define HID2     128
#define NHID     64

typedef __attribute__((ext_vector_type(8))) short bf16x8;
typedef __attribute__((ext_vector_type(4))) float f32x4;
typedef __attribute__((ext_vector_type(4))) unsigned short us4;

__device__ __forceinline__ float selu_f(float x) {
    const float alpha = 1.6732632423543772f;
    const float scale = 1.0507009873554805f;
    return scale * (x > 0.f ? x : alpha * (expf(x) - 1.f));
}

// round-to-nearest-even fp32 -> bf16
__device__ __forceinline__ unsigned short f2bf(float f) {
    unsigned u = __float_as_uint(f);
    u += 0x7FFFu + ((u >> 16) & 1u);
    return (unsigned short)(u >> 16);
}
__device__ __forceinline__ float bflo(unsigned q) { return __uint_as_float(q << 16); }
__device__ __forceinline__ float bfhi(unsigned q) { return __uint_as_float(q & 0xffff0000u); }

// ---------------- setup: zero deg + e-buffers, convert/transpose both weight matrices ----------------
__global__ void setup_k(const float* __restrict__ W1, const float* __restrict__ W2,
                        unsigned short* __restrict__ Wt1, unsigned short* __restrict__ Wt2,
                        unsigned* __restrict__ deg,
                        float* __restrict__ es1, float* __restrict__ ed1,
                        float* __restrict__ es2, float* __restrict__ ed2) {
    int i = blockIdx.x * blockDim.x + threadIdx.x;
    if (i < N_NODES) {
        deg[i] = 0u;
        es1[i] = 0.f; ed1[i] = 0.f;
        es2[i] = 0.f; ed2[i] = 0.f;
    }
    if (i < 128 * IN_F) {
        int n = i / IN_F, k = i - n * IN_F;
        Wt1[i] = f2bf(W1[(long)k * 128 + n]);
    }
    if (i < 128 * HID2) {
        int n = i >> 7, k = i & 127;
        Wt2[i] = f2bf(W2[(long)k * 128 + n]);
    }
}

// ---------------- GEMM: bf16 MFMA, M64/BK64, reg-prefetch; fused e_src/e_dst epilogue ----------------
#define LDA2 72   // padded LDS row stride (bf16): 144 B; frag reads conflict-free
template<bool ABF16, bool OUTBF16>
__global__ __launch_bounds__(256) void gemm_mfma(
        const void* __restrict__ Av, const unsigned short* __restrict__ Bt,
        void* __restrict__ Cv, int M, int K,
        const float* __restrict__ a_s, const float* __restrict__ a_d,
        float* __restrict__ es, float* __restrict__ ed) {
    __shared__ unsigned short As[64 * LDA2];    // 9.2 KB
    __shared__ unsigned short Bs[128 * LDA2];   // 18.4 KB
    const float* Af = (const float*)Av;
    const unsigned short* Ab = (const unsigned short*)Av;
    const int tid  = threadIdx.x;
    const int row0 = blockIdx.x * 64;
    const int w    = tid >> 6;
    const int lane = tid & 63;
    const int quad = lane >> 4;
    const int l16  = lane & 15;
    const int m_off = (w & 1) * 32;   // wave covers 32 rows
    const int n_off = (w >> 1) * 64;  // x 64 cols

    f32x4 acc[2][4];
#pragma unroll
    for (int mi = 0; mi < 2; mi++)
#pragma unroll
        for (int ni = 0; ni < 4; ni++)
            acc[mi][ni] = (f32x4){0.f, 0.f, 0.f, 0.f};

    float4 aR[4];
    bf16x8 aRb[2];
    bf16x8 bR[4];
    if (ABF16) {
#pragma unroll
        for (int i = 0; i < 2; i++) {
            int p = tid + i * 256;
            int r = p >> 3, c8 = p & 7;
            int gr = row0 + r;
            aRb[i] = (gr < M) ? *(const bf16x8*)&Ab[(long)gr * K + c8 * 8]
                              : (bf16x8){0,0,0,0,0,0,0,0};
        }
    } else {
#pragma unroll
        for (int i = 0; i < 4; i++) {
            int p = tid + i * 256;
            int r = p >> 4, c4 = p & 15;
            int gr = row0 + r;
            aR[i] = (gr < M) ? *(const float4*)&Af[(long)gr * K + c4 * 4]
                             : make_float4(0.f, 0.f, 0.f, 0.f);
        }
    }
#pragma unroll
    for (int i = 0; i < 4; i++) {
        int c = tid + i * 256;
        int n = c >> 3, koff = (c & 7) * 8;
        bR[i] = *(const bf16x8*)&Bt[(long)n * K + koff];
    }

    for (int k0 = 0; k0 < K; k0 += 64) {
        if (ABF16) {
#pragma unroll
            for (int i = 0; i < 2; i++) {
                int p = tid + i * 256;
                int r = p >> 3, c8 = p & 7;
                *(bf16x8*)&As[r * LDA2 + c8 * 8] = aRb[i];
            }
        } else {
#pragma unroll
            for (int i = 0; i < 4; i++) {
                int p = tid + i * 256;
                int r = p >> 4, c4 = p & 15;
                us4 o;
                o.x = f2bf(aR[i].x); o.y = f2bf(aR[i].y);
                o.z = f2bf(aR[i].z); o.w = f2bf(aR[i].w);
                *(us4*)&As[r * LDA2 + c4 * 4] = o;
            }
        }
#pragma unroll
        for (int i = 0; i < 4; i++) {
            int c = tid + i * 256;
            int n = c >> 3, koff = (c & 7) * 8;
            *(bf16x8*)&Bs[n * LDA2 + koff] = bR[i];
        }
        __syncthreads();

        if (k0 + 64 < K) {
            int k1 = k0 + 64;
            if (ABF16) {
#pragma unroll
                for (int i = 0; i < 2; i++) {
                    int p = tid + i * 256;
                    int r = p >> 3, c8 = p & 7;
                    int gr = row0 + r;
                    aRb[i] = (gr < M) ? *(const bf16x8*)&Ab[(long)gr * K + k1 + c8 * 8]
                                      : (bf16x8){0,0,0,0,0,0,0,0};
                }
            } else {
#pragma unroll
                for (int i = 0; i < 4; i++) {
                    int p = tid + i * 256;
                    int r = p >> 4, c4 = p & 15;
                    int gr = row0 + r;
                    aR[i] = (gr < M) ? *(const float4*)&Af[(long)gr * K + k1 + c4 * 4]
                                     : make_float4(0.f, 0.f, 0.f, 0.f);
                }
            }
#pragma unroll
            for (int i = 0; i < 4; i++) {
                int c = tid + i * 256;
                int n = c >> 3, koff = (c & 7) * 8;
                bR[i] = *(const bf16x8*)&Bt[(long)n * K + k1 + koff];
            }
        }

        bf16x8 af[2][2], bfr[2][4];
#pragma unroll
        for (int kk = 0; kk < 2; kk++) {
#pragma unroll
            for (int mi = 0; mi < 2; mi++)
                af[kk][mi] = *(const bf16x8*)&As[(m_off + mi * 16 + l16) * LDA2 + kk * 32 + quad * 8];
#pragma unroll
            for (int ni = 0; ni < 4; ni++)
                bfr[kk][ni] = *(const bf16x8*)&Bs[(n_off + ni * 16 + l16) * LDA2 + kk * 32 + quad * 8];
        }
#pragma unroll
        for (int kk = 0; kk < 2; kk++)
#pragma unroll
            for (int mi = 0; mi < 2; mi++)
#pragma unroll
                for (int ni = 0; ni < 4; ni++)
                    acc[mi][ni] = __builtin_amdgcn_mfma_f32_16x16x32_bf16(
                        af[kk][mi], bfr[kk][ni], acc[mi][ni], 0, 0, 0);
        __syncthreads();
    }

    // attention-vector partials for this lane's 4 cols
    float as_v[4], ad_v[4];
#pragma unroll
    for (int ni = 0; ni < 4; ni++) {
        int col = n_off + ni * 16 + l16;
        as_v[ni] = a_s[col];
        ad_v[ni] = a_d[col];
    }

    // epilogue: D row = m_off+mi*16+quad*4+r, col = n_off+ni*16+l16
#pragma unroll
    for (int mi = 0; mi < 2; mi++)
#pragma unroll
        for (int r = 0; r < 4; r++) {
            int row = row0 + m_off + mi * 16 + quad * 4 + r;
            float ps = 0.f, pd = 0.f;
#pragma unroll
            for (int ni = 0; ni < 4; ni++) {
                float v = acc[mi][ni][r];
                ps = fmaf(v, as_v[ni], ps);
                pd = fmaf(v, ad_v[ni], pd);
            }
#pragma unroll
            for (int o = 1; o < 16; o <<= 1) {
                ps += __shfl_xor(ps, o);
                pd += __shfl_xor(pd, o);
            }
            if (row < M) {
                if (l16 == 0) {
                    atomicAdd(es + row, ps);
                    atomicAdd(ed + row, pd);
                }
                if (OUTBF16) {
                    unsigned short* C16 = (unsigned short*)Cv;
#pragma unroll
                    for (int ni = 0; ni < 4; ni++)
                        C16[(long)row * 128 + n_off + ni * 16 + l16] = f2bf(acc[mi][ni][r]);
                } else {
                    float* Cf = (float*)Cv;
#pragma unroll
                    for (int ni = 0; ni < 4; ni++)
                        Cf[(long)row * 128 + n_off + ni * 16 + l16] = acc[mi][ni][r];
                }
            }
        }
}

// ---------------- CSR build ----------------
__global__ void deg_hist(const int* __restrict__ ei, unsigned* __restrict__ deg) {
    int e = blockIdx.x * blockDim.x + threadIdx.x;
    if (e < N_EDGES) atomicAdd(&deg[ei[N_EDGES + e]], 1u);
}

// exclusive scan of (deg+1) -> row_ptr, fused with self-loop seed + cursor init.
__global__ __launch_bounds__(256) void scan_seed(const unsigned* __restrict__ deg,
                                                 unsigned* __restrict__ row_ptr,
                                                 unsigned* __restrict__ cursor,
                                                 unsigned* __restrict__ csr_src) {
    __shared__ unsigned psum_s[4];
    __shared__ unsigned wsum[4];
    int tid = threadIdx.x;
    int wid = tid >> 6, lane = tid & 63;
    int chunk0 = blockIdx.x * 256;

    unsigned psum = 0;
    for (int i = tid; i < chunk0; i += 256) psum += deg[i] + 1u;
    for (int o = 32; o; o >>= 1) psum += __shfl_xor(psum, o);
    if (lane == 0) psum_s[wid] = psum;

    int i = chunk0 + tid;
    unsigned v = (i < N_NODES) ? deg[i] + 1u : 0u;
    unsigned x = v;
    for (int o = 1; o < 64; o <<= 1) {
        unsigned y = __shfl_up(x, o);
        if (lane >= o) x += y;
    }
    if (lane == 63) wsum[wid] = x;
    __syncthreads();
    unsigned base = psum_s[0] + psum_s[1] + psum_s[2] + psum_s[3];
    unsigned wbase = 0;
    for (int k = 0; k < wid; k++) wbase += wsum[k];
    if (i < N_NODES) {
        unsigned rp = base + wbase + x - v;
        row_ptr[i] = rp;
        csr_src[rp] = (unsigned)i;   // self-loop first
        cursor[i] = rp + 1;
        if (i == N_NODES - 1) row_ptr[N_NODES] = rp + v;
    }
}

__global__ void csr_scatter(const int* __restrict__ ei,
                            unsigned* __restrict__ cursor, unsigned* __restrict__ csr_src) {
    int e = blockIdx.x * blockDim.x + threadIdx.x;
    if (e >= N_EDGES) return;
    int d = ei[N_EDGES + e];
    unsigned p = atomicAdd(&cursor[d], 1u);
    csr_src[p] = (unsigned)ei[e];
}

// ---------------- fused GAT tail: single edge pass, half-wave edge pairs ----------------
// wave per dst node; half-wave (32 lanes) per edge of a pair; lane covers features fl*4..fl*4+3
template<bool OUTBF16>
__global__ __launch_bounds__(256) void gat_agg(
        const unsigned* __restrict__ row_ptr, const unsigned* __restrict__ csr_src,
        const float* __restrict__ e_src, const float* __restrict__ e_dst,
        const unsigned short* __restrict__ xw, const float* __restrict__ bias,
        void* __restrict__ outv) {
    __shared__ float2 buf[4][64];     // (num, src-bits) per wave
    int wv = threadIdx.x >> 6;
    int node = blockIdx.x * 4 + wv;
    if (node >= N_NODES) return;
    int lane = threadIdx.x & 63;
    int half = lane >> 5;
    int fl   = lane & 31;
    unsigned beg = row_ptr[node], end = row_ptr[node + 1];
    int deg = (int)(end - beg);
    float ed = e_dst[node];
    const unsigned short* xwf = xw + fl * 4;

    float ax = 0.f, ay = 0.f, az = 0.f, aw = 0.f, den = 0.f;
    for (int base = 0; base < deg; base += 64) {
        int i = base + lane;
        float num = 0.f;
        unsigned s = 0u;
        if (i < deg) {
            s = csr_src[beg + i];
            float e = e_src[s] + ed;
            e = e > 0.f ? e : 0.2f * e;
            num = __expf(e);
            den += num;
        }
        float2 pk; pk.x = num; pk.y = __uint_as_float(s);
        buf[wv][lane] = pk;   // all 64 slots written (num=0 pad beyond deg)

        int cnt = deg - base; if (cnt > 64) cnt = 64;
        int steps = (cnt + 1) >> 1;   // edge pairs; this half takes edge 2t+half
        int t = 0;
        for (; t + 4 <= steps; t += 4) {
            float2 p0 = buf[wv][2 * (t + 0) + half];
            float2 p1 = buf[wv][2 * (t + 1) + half];
            float2 p2 = buf[wv][2 * (t + 2) + half];
            float2 p3 = buf[wv][2 * (t + 3) + half];
            uint2 q0 = *(const uint2*)&xwf[(long)__float_as_uint(p0.y) * HID2];
            uint2 q1 = *(const uint2*)&xwf[(long)__float_as_uint(p1.y) * HID2];
            uint2 q2 = *(const uint2*)&xwf[(long)__float_as_uint(p2.y) * HID2];
            uint2 q3 = *(const uint2*)&xwf[(long)__float_as_uint(p3.y) * HID2];
            ax = fmaf(p0.x, bflo(q0.x), ax); ay = fmaf(p0.x, bfhi(q0.x), ay);
            az = fmaf(p0.x, bflo(q0.y), az); aw = fmaf(p0.x, bfhi(q0.y), aw);
            ax = fmaf(p1.x, bflo(q1.x), ax); ay = fmaf(p1.x, bfhi(q1.x), ay);
            az = fmaf(p1.x, bflo(q1.y), az); aw = fmaf(p1.x, bfhi(q1.y), aw);
            ax = fmaf(p2.x, bflo(q2.x), ax); ay = fmaf(p2.x, bfhi(q2.x), ay);
            az = fmaf(p2.x, bflo(q2.y), az); aw = fmaf(p2.x, bfhi(q2.y), aw);
            ax = fmaf(p3.x, bflo(q3.x), ax); ay = fmaf(p3.x, bfhi(q3.x), ay);
            az = fmaf(p3.x, bflo(q3.y), az); aw = fmaf(p3.x, bfhi(q3.y), aw);
        }
        for (; t < steps; t++) {
            float2 p = buf[wv][2 * t + half];
            uint2 q = *(const uint2*)&xwf[(long)__float_as_uint(p.y) * HID2];
            ax = fmaf(p.x, bflo(q.x), ax); ay = fmaf(p.x, bfhi(q.x), ay);
            az = fmaf(p.x, bflo(q.y), az); aw = fmaf(p.x, bfhi(q.y), aw);
        }
    }
    // merge the two edge-parity halves; reduce den across all 64 lanes
    ax += __shfl_xor(ax, 32); ay += __shfl_xor(ay, 32);
    az += __shfl_xor(az, 32); aw += __shfl_xor(aw, 32);
    for (int o = 32; o; o >>= 1) den += __shfl_xor(den, o);
    float inv = 1.f / den;
    float v0 = selu_f(fmaf(ax, inv, bias[fl * 4 + 0]));
    float v1 = selu_f(fmaf(ay, inv, bias[fl * 4 + 1]));
    float v2 = selu_f(fmaf(az, inv, bias[fl * 4 + 2]));
    float v3 = selu_f(fmaf(aw, inv, bias[fl * 4 + 3]));
    if (half == 0) {
        if (OUTBF16) {
            uint2 o;
            o.x = ((unsigned)f2bf(v1) << 16) | (unsigned)f2bf(v0);
            o.y = ((unsigned)f2bf(v3) << 16) | (unsigned)f2bf(v2);
            *(uint2*)((unsigned short*)outv + (long)node * HID2 + fl * 4) = o;
        } else {
            float4 o = make_float4(v0, v1, v2, v3);
            *(float4*)((float*)outv + (long)node * HID2 + fl * 4) = o;
        }
    }
}

// ---------------- fused pool + fc1 + fc2 + log_softmax: one block per graph ----------------
__global__ __launch_bounds__(256) void pool_head(
        const float* __restrict__ h, const int* __restrict__ batch,
        const float* __restrict__ fc1w, const float* __restrict__ fc1b,
        const float* __restrict__ fc2w, const float* __restrict__ fc2b,
        float* __restrict__ out) {
    __shared__ float pooled_s[HID2];
    __shared__ float part[HID2];
    __shared__ float g_s[NHID];
    int g = blockIdx.x;
    int lo = 0, hi = N_NODES;
    while (lo < hi) { int mid = (lo + hi) >> 1; if (batch[mid] < g) lo = mid + 1; else hi = mid; }
    int start = lo;
    hi = N_NODES;
    while (lo < hi) { int mid = (lo + hi) >> 1; if (batch[mid] < g + 1) lo = mid + 1; else hi = mid; }
    int end = lo;

    int f = threadIdx.x & 127, half = threadIdx.x >> 7;
    float acc = 0.f;
    for (int n = start + half; n < end; n += 2) acc += h[(long)n * HID2 + f];
    if (half == 0) part[f] = acc;
    __syncthreads();
    if (half == 1) {
        float c = (float)(end - start);
        c = c > 1.f ? c : 1.f;
        pooled_s[f] = selu_f((part[f] + acc) / c);
    }
    __syncthreads();
    int j = threadIdx.x;
    if (j < NHID) {
        float a = fc1b[j];
#pragma unroll
        for (int k = 0; k < HID2; k++) a = fmaf(pooled_s[k], fc1w[k * NHID + j], a);
        g_s[j] = selu_f(a);
    }
    __syncthreads();
    if (j == 0) {
        float l0 = fc2b[0], l1 = fc2b[1];
#pragma unroll
        for (int k = 0; k < NHID; k++) {
            float v = g_s[k];
            l0 = fmaf(v, fc2w[2 * k + 0], l0);
            l1 = fmaf(v, fc2w[2 * k + 1], l1);
        }
        float m = fmaxf(l0, l1);
        float lse = m + logf(expf(l0 - m) + expf(l1 - m));
        out[g * 2 + 0] = l0 - lse;
        out[g * 2 + 1] = l1 - lse;
    }
}

extern "C" void kernel_launch(void* const* d_in, const int* in_sizes, int n_in,
                              void* d_out, int out_size, void* d_ws, size_t ws_size,
                              hipStream_t stream) {
    const float* x     = (const float*)d_in[0];
    const int*   ei    = (const int*)d_in[1];
    const int*   batch = (const int*)d_in[2];
    const float* W1    = (const float*)d_in[3];
    const float* as1   = (const float*)d_in[4];
    const float* ad1   = (const float*)d_in[5];
    const float* b1    = (const float*)d_in[6];
    const float* W2    = (const float*)d_in[7];
    const float* as2   = (const float*)d_in[8];
    const float* ad2   = (const float*)d_in[9];
    const float* b2    = (const float*)d_in[10];
    const float* fc1w  = (const float*)d_in[11];
    const float* fc1b  = (const float*)d_in[12];
    const float* fc2w  = (const float*)d_in[13];
    const float* fc2b  = (const float*)d_in[14];
    float* out = (float*)d_out;

    // workspace layout
    const long NH = (long)N_NODES * HID2;        // 6.4M elems
    unsigned short* xwb = (unsigned short*)d_ws;         // NH bf16 (xw, both layers)
    unsigned short* h1b = xwb + NH;                      // NH bf16 (h1)
    float*    B2      = (float*)(h1b + NH);              // NH f32 (h2, for pooling)
    float*    es1     = B2 + NH;
    float*    ed1     = es1 + N_NODES;
    float*    es2     = ed1 + N_NODES;
    float*    ed2     = es2 + N_NODES;
    unsigned* deg     = (unsigned*)(ed2 + N_NODES);
    unsigned* cursor  = deg + N_NODES;
    unsigned* row_ptr = cursor + N_NODES;               // N_NODES+1
    unsigned* csr_src = row_ptr + N_NODES + 1;          // E_TOT
    unsigned short* Wt1 = (unsigned short*)(csr_src + E_TOT);  // 128x768 bf16
    unsigned short* Wt2 = Wt1 + 128 * IN_F;                    // 128x128 bf16

    const int TB = 256;
    const int gNode = (N_NODES + TB - 1) / TB;
    const int gEdge = (N_EDGES + TB - 1) / TB;
    const int gGemm = (N_NODES + 63) / 64;
    const int gAgg  = (N_NODES + 3) / 4;

    // setup (zero deg + e-buffers, weight converts) + CSR build
    setup_k<<<(128 * IN_F + TB - 1) / TB, TB, 0, stream>>>(W1, W2, Wt1, Wt2, deg,
                                                           es1, ed1, es2, ed2);
    deg_hist<<<gEdge, TB, 0, stream>>>(ei, deg);
    scan_seed<<<gNode, TB, 0, stream>>>(deg, row_ptr, cursor, csr_src);
    csr_scatter<<<gEdge, TB, 0, stream>>>(ei, cursor, csr_src);

    // ---- layer 1 ----
    gemm_mfma<false, true><<<gGemm, 256, 0, stream>>>(x, Wt1, xwb, N_NODES, IN_F,
                                                      as1, ad1, es1, ed1);
    gat_agg<true><<<gAgg, 256, 0, stream>>>(row_ptr, csr_src, es1, ed1, xwb, b1, h1b);

    // ---- layer 2 ----
    gemm_mfma<true, true><<<gGemm, 256, 0, stream>>>(h1b, Wt2, xwb, N_NODES, HID2,
                                                     as2, ad2, es2, ed2);
    gat_agg<false><<<gAgg, 256, 0, stream>>>(row_ptr, csr_src, es2, ed2, xwb, b2, B2);

    // ---- pool + head (fused) ----
    pool_head<<<N_GRAPHS, 256, 0, stream>>>(B2, batch, fc1w, fc1b, fc2w, fc2b, out);
}